// Round 1
// baseline (602.804 us; speedup 1.0000x reference)
//
#include <hip/hip_runtime.h>
#include <math.h>

#define LL 1024
#define DD 512
#define NB 8
#define KTOP 20

// ================= transpose x [B,L,D] -> xT [B,D,L] =================
__global__ __launch_bounds__(256) void k_transpose(const float* __restrict__ x,
                                                   float* __restrict__ xT) {
  __shared__ float T[64][65];
  int b = blockIdx.z;
  int t0 = blockIdx.x * 64, c0 = blockIdx.y * 64;
  int tid = threadIdx.x;
  int lane = tid & 63, row4 = tid >> 6;
#pragma unroll
  for (int it = 0; it < 16; ++it) {
    int tl = it * 4 + row4;
    T[lane][tl] = x[((size_t)b * LL + t0 + tl) * DD + c0 + lane];
  }
  __syncthreads();
#pragma unroll
  for (int it = 0; it < 16; ++it) {
    int cl = it * 4 + row4;
    xT[((size_t)b * DD + c0 + cl) * LL + t0 + lane] = T[cl][lane];
  }
}

// ================= GEMM: C[8192,512] = A[8192,512] @ W[512,512] =================
// MODE 0: A row-major (x or h1), out = transposed channel-major [B,D,L], +bias  (QKV)
// MODE 1: A read from channel-major xsT (A^T layout), out token-major, bias+ReLU (FFN1)
// MODE 2: A row-major (h1), out token-major, bias + residual from xsT           (FFN2)
#define BM 128
#define BN 64
#define BK 16

template <int MODE>
__global__ __launch_bounds__(256) void k_gemm(const float* __restrict__ A,
                                              const float* __restrict__ W,
                                              const float* __restrict__ bias,
                                              const float* __restrict__ resT,
                                              float* out) {
  __shared__ float smem[BM * (BN + 1)];  // 33.3 KB, aliased: As/Bs then Cs/Xs
  float(*As)[BM] = (float(*)[BM])smem;            // [BK][BM]
  float(*Bs)[BN] = (float(*)[BN])(smem + BK * BM);  // [BK][BN]

  int tid = threadIdx.x;
  int tx = tid & 15, ty = tid >> 4;
  int n0 = blockIdx.x * BN;
  int m0 = blockIdx.y * BM;
  int b = m0 >> 10, t0 = m0 & (LL - 1);

  float acc[8][4];
#pragma unroll
  for (int i = 0; i < 8; ++i)
#pragma unroll
    for (int j = 0; j < 4; ++j) acc[i][j] = 0.f;

  for (int k0 = 0; k0 < DD; k0 += BK) {
    if (MODE == 1) {
      // A^T layout: As[k][m] = xsT[b][k0+k][t0+m]
      int k = tid >> 4, m8 = (tid & 15) * 8;
      const float* src = A + ((size_t)b * DD + k0 + k) * LL + t0 + m8;
      float4 v0 = *(const float4*)src;
      float4 v1 = *(const float4*)(src + 4);
      *(float4*)&As[k][m8] = v0;
      *(float4*)&As[k][m8 + 4] = v1;
    } else {
      // row-major: As[k][m] = A[(m0+m)*512 + k0+k]
      int m = tid >> 1, kq = (tid & 1) * 8;
      const float* src = A + (size_t)(m0 + m) * DD + k0 + kq;
      float4 v0 = *(const float4*)src;
      float4 v1 = *(const float4*)(src + 4);
      As[kq + 0][m] = v0.x; As[kq + 1][m] = v0.y;
      As[kq + 2][m] = v0.z; As[kq + 3][m] = v0.w;
      As[kq + 4][m] = v1.x; As[kq + 5][m] = v1.y;
      As[kq + 6][m] = v1.z; As[kq + 7][m] = v1.w;
    }
    {
      int k = tid >> 4, n4 = (tid & 15) * 4;
      *(float4*)&Bs[k][n4] = *(const float4*)(W + (size_t)(k0 + k) * DD + n0 + n4);
    }
    __syncthreads();
#pragma unroll
    for (int kk = 0; kk < BK; ++kk) {
      float a[8], bb[4];
      *(float4*)&a[0] = *(const float4*)&As[kk][ty * 8];
      *(float4*)&a[4] = *(const float4*)&As[kk][ty * 8 + 4];
      *(float4*)&bb[0] = *(const float4*)&Bs[kk][tx * 4];
#pragma unroll
      for (int i = 0; i < 8; ++i)
#pragma unroll
        for (int j = 0; j < 4; ++j) acc[i][j] += a[i] * bb[j];
    }
    __syncthreads();
  }

  if (MODE == 0) {
    // transposed write: out[(b*D + n)*L + t] ; bounce through LDS
    float(*Cs)[BN + 1] = (float(*)[BN + 1])smem;
#pragma unroll
    for (int j = 0; j < 4; ++j) {
      float bv = bias[n0 + tx * 4 + j];
#pragma unroll
      for (int i = 0; i < 8; ++i) Cs[ty * 8 + i][tx * 4 + j] = acc[i][j] + bv;
    }
    __syncthreads();
#pragma unroll
    for (int it = 0; it < 32; ++it) {
      int n = it * 2 + (tid >> 7);
      int m = tid & 127;
      out[((size_t)b * DD + n0 + n) * LL + t0 + m] = Cs[m][n];
    }
  } else {
    if (MODE == 2) {
      float(*Xs)[BN + 1] = (float(*)[BN + 1])smem;
#pragma unroll
      for (int it = 0; it < 32; ++it) {
        int n = it * 2 + (tid >> 7);
        int m = tid & 127;
        Xs[m][n] = resT[((size_t)b * DD + n0 + n) * LL + t0 + m];
      }
      __syncthreads();
#pragma unroll
      for (int i = 0; i < 8; ++i)
#pragma unroll
        for (int j = 0; j < 4; ++j) acc[i][j] += Xs[ty * 8 + i][tx * 4 + j];
    }
    float bv[4];
#pragma unroll
    for (int j = 0; j < 4; ++j) bv[j] = bias[n0 + tx * 4 + j];
#pragma unroll
    for (int i = 0; i < 8; ++i) {
      float4 v;
      v.x = acc[i][0] + bv[0];
      v.y = acc[i][1] + bv[1];
      v.z = acc[i][2] + bv[2];
      v.w = acc[i][3] + bv[3];
      if (MODE == 1) {
        v.x = fmaxf(v.x, 0.f); v.y = fmaxf(v.y, 0.f);
        v.z = fmaxf(v.z, 0.f); v.w = fmaxf(v.w, 0.f);
      }
      *(float4*)&out[(size_t)(m0 + ty * 8 + i) * DD + n0 + tx * 4] = v;
    }
  }
}

// ================= autocorr + topk + softmax + aggregate + decomp1 =================
// one workgroup per (b, channel); QT may alias xsT (read-before-write per row)
__global__ __launch_bounds__(256) void k_autocorr(const float* QT,
                                                  const float* __restrict__ KT,
                                                  const float* __restrict__ VT,
                                                  const float* __restrict__ xT,
                                                  float* xsT) {
  __shared__ float Qs[LL], Vs[LL], Xs[LL];
  __shared__ float Ks2[2112];      // K duplicated (2048) + skew(a + a>>5)
  __shared__ float Cp[4][LL];      // quarter partials -> Cp[0]=corr, Cp[1]=series
  __shared__ float wrv[4];
  __shared__ int wri[4];
  __shared__ float wv[KTOP];
  __shared__ int wi[KTOP];

  int tid = threadIdx.x;
  size_t base = (size_t)blockIdx.x * LL;

  *(float4*)&Qs[tid * 4] = *(const float4*)(QT + base + tid * 4);
  *(float4*)&Vs[tid * 4] = *(const float4*)(VT + base + tid * 4);
  *(float4*)&Xs[tid * 4] = *(const float4*)(xT + base + tid * 4);
  for (int i = tid; i < 2048; i += 256)
    Ks2[i + (i >> 5)] = KT[base + (i & (LL - 1))];
  __syncthreads();

  // ---- Corr[tau] = sum_t Q[t] * K[(t - tau) mod L] ----
  {
    int g = tid & 63, quarter = tid >> 6;
    int tau0 = g * 16;
    float acc[16];
#pragma unroll
    for (int j = 0; j < 16; ++j) acc[j] = 0.f;
    int tbase = quarter * 256;
#pragma unroll 1
    for (int s8 = 0; s8 < 256; s8 += 8) {
      int t0 = tbase + s8;
      float q[8];
      *(float4*)&q[0] = *(const float4*)&Qs[t0];
      *(float4*)&q[4] = *(const float4*)&Qs[t0 + 4];
      int kb = t0 - tau0 - 15 + 1024;  // in [1, 2025]
      float kk[23];
#pragma unroll
      for (int m = 0; m < 23; ++m) {
        int a2 = kb + m;
        kk[m] = Ks2[a2 + (a2 >> 5)];
      }
#pragma unroll
      for (int j = 0; j < 16; ++j) {
        float aj = acc[j];
#pragma unroll
        for (int i = 0; i < 8; ++i) aj += q[i] * kk[15 + i - j];
        acc[j] = aj;
      }
    }
#pragma unroll
    for (int j = 0; j < 16; ++j) Cp[quarter][tau0 + j] = acc[j];
  }
  __syncthreads();
#pragma unroll
  for (int i = 0; i < 4; ++i) {
    int idx = tid + 256 * i;
    Cp[0][idx] += Cp[1][idx] + Cp[2][idx] + Cp[3][idx];
  }
  __syncthreads();

  // ---- top-20 (lowest-index tie-break, like jax.lax.top_k) ----
  for (int sel = 0; sel < KTOP; ++sel) {
    float best = -3.0e38f;
    int bidx = 0;
#pragma unroll
    for (int i = 0; i < 4; ++i) {
      int idx = tid + 256 * i;
      float v = Cp[0][idx];
      if (v > best) { best = v; bidx = idx; }
    }
#pragma unroll
    for (int off = 32; off > 0; off >>= 1) {
      float v2 = __shfl_xor(best, off);
      int i2 = __shfl_xor(bidx, off);
      if (v2 > best || (v2 == best && i2 < bidx)) { best = v2; bidx = i2; }
    }
    if ((tid & 63) == 0) { wrv[tid >> 6] = best; wri[tid >> 6] = bidx; }
    __syncthreads();
    if (tid == 0) {
      for (int w = 1; w < 4; ++w)
        if (wrv[w] > best || (wrv[w] == best && wri[w] < bidx)) {
          best = wrv[w]; bidx = wri[w];
        }
      wv[sel] = best;
      wi[sel] = bidx;
      Cp[0][bidx] = -3.0e38f;
    }
    __syncthreads();
  }

  // ---- softmax over the 20 weights ----
  if (tid == 0) {
    float mx = wv[0];
    for (int k = 1; k < KTOP; ++k) mx = fmaxf(mx, wv[k]);
    float s = 0.f;
    for (int k = 0; k < KTOP; ++k) {
      float e = expf(wv[k] - mx);
      wv[k] = e;
      s += e;
    }
    float inv = 1.f / s;
    for (int k = 0; k < KTOP; ++k) wv[k] *= inv;
  }
  __syncthreads();

  // ---- aggregate (saturating shift) + residual ----
#pragma unroll
  for (int i = 0; i < 4; ++i) {
    int t = tid + 256 * i;
    float r = 0.f;
    for (int k = 0; k < KTOP; ++k) {
      int p = wi[k] + t;
      p = p < (LL - 1) ? p : (LL - 1);
      r += wv[k] * Vs[p];
    }
    Cp[1][t] = r + Xs[t];
  }
  __syncthreads();

  // ---- series_decomp #1: x_s = s - movavg25(s), zero-padded, /25 always ----
#pragma unroll
  for (int i = 0; i < 4; ++i) {
    int t = tid + 256 * i;
    int lo = t - 12; lo = lo < 0 ? 0 : lo;
    int hi = t + 12; hi = hi > LL - 1 ? LL - 1 : hi;
    float s = 0.f;
    for (int j = lo; j <= hi; ++j) s += Cp[1][j];
    xsT[base + t] = Cp[1][t] - s / 25.0f;
  }
}

// ================= final series_decomp on s2 [B,L,D] (token-major) =================
#define TCH 64
__global__ __launch_bounds__(256) void k_decomp2(const float* __restrict__ s2,
                                                 float* __restrict__ out) {
  int b = blockIdx.z;
  int c = blockIdx.y * 256 + threadIdx.x;
  int t0 = blockIdx.x * TCH;
  const float* p = s2 + (size_t)b * LL * DD + c;
  float* o = out + (size_t)b * LL * DD + c;
  float wsum = 0.f;
  int lo = t0 - 12; lo = lo < 0 ? 0 : lo;
  int hi = t0 + 12; hi = hi > LL - 1 ? LL - 1 : hi;
  for (int j = lo; j <= hi; ++j) wsum += p[(size_t)j * DD];
  for (int t = t0; t < t0 + TCH; ++t) {
    float center = p[(size_t)t * DD];
    o[(size_t)t * DD] = center - wsum / 25.0f;
    float addv = (t + 13 < LL) ? p[(size_t)(t + 13) * DD] : 0.f;
    float subv = (t - 12 >= 0) ? p[(size_t)(t - 12) * DD] : 0.f;
    wsum += addv - subv;
  }
}

// ================= launch =================
extern "C" void kernel_launch(void* const* d_in, const int* in_sizes, int n_in,
                              void* d_out, int out_size, void* d_ws, size_t ws_size,
                              hipStream_t stream) {
  const float* x  = (const float*)d_in[0];
  const float* Wq = (const float*)d_in[1];
  const float* bq = (const float*)d_in[2];
  const float* Wk = (const float*)d_in[3];
  const float* bk = (const float*)d_in[4];
  const float* Wv = (const float*)d_in[5];
  const float* bv = (const float*)d_in[6];
  const float* W1 = (const float*)d_in[7];
  const float* b1 = (const float*)d_in[8];
  const float* W2 = (const float*)d_in[9];
  const float* b2 = (const float*)d_in[10];
  float* out = (float*)d_out;
  float* ws = (float*)d_ws;

  const size_t SZ = (size_t)NB * DD * LL;  // 4,194,304 floats per [B,D,L] buffer
  float* xT  = ws;            // [B,D,L]
  float* QT  = ws + SZ;       // [B,D,L]
  float* KT  = ws + 2 * SZ;   // [B,D,L]
  float* VT  = ws + 3 * SZ;   // [B,D,L]
  float* xsT = QT;            // autocorr overwrites its own Q row (safe)
  float* h1  = xT;            // xT dead after autocorr
  float* s2  = KT;            // KT dead after autocorr
  // peak ws usage: 4 * SZ * 4B = 64 MiB

  k_transpose<<<dim3(16, 8, NB), 256, 0, stream>>>(x, xT);

  k_gemm<0><<<dim3(8, 64), 256, 0, stream>>>(x, Wq, bq, nullptr, QT);
  k_gemm<0><<<dim3(8, 64), 256, 0, stream>>>(x, Wk, bk, nullptr, KT);
  k_gemm<0><<<dim3(8, 64), 256, 0, stream>>>(x, Wv, bv, nullptr, VT);

  k_autocorr<<<dim3(NB * DD), 256, 0, stream>>>(QT, KT, VT, xT, xsT);

  k_gemm<1><<<dim3(8, 64), 256, 0, stream>>>(xsT, W1, b1, nullptr, h1);
  k_gemm<2><<<dim3(8, 64), 256, 0, stream>>>(h1, W2, b2, xsT, s2);

  k_decomp2<<<dim3(LL / TCH, DD / 256, NB), 256, 0, stream>>>(s2, out);
}

// Round 3
// 545.481 us; speedup vs baseline: 1.1051x; 1.1051x over previous
//
#include <hip/hip_runtime.h>
#include <math.h>

#define LL 1024
#define DD 512
#define NB 8
#define KTOP 20

// ================= transpose x [B,L,D] -> xT [B,D,L] =================
__global__ __launch_bounds__(256) void k_transpose(const float* __restrict__ x,
                                                   float* __restrict__ xT) {
  __shared__ float T[64][65];
  int b = blockIdx.z;
  int t0 = blockIdx.x * 64, c0 = blockIdx.y * 64;
  int tid = threadIdx.x;
  int lane = tid & 63, row4 = tid >> 6;
#pragma unroll
  for (int it = 0; it < 16; ++it) {
    int tl = it * 4 + row4;
    T[lane][tl] = x[((size_t)b * LL + t0 + tl) * DD + c0 + lane];
  }
  __syncthreads();
#pragma unroll
  for (int it = 0; it < 16; ++it) {
    int cl = it * 4 + row4;
    xT[((size_t)b * DD + c0 + cl) * LL + t0 + lane] = T[cl][lane];
  }
}

// ================= GEMM: C[8192,512] = A[8192,512] @ W[512,512] =================
#define BM 128
#define BN 64
#define BK 16

template <int MODE>
__global__ __launch_bounds__(256) void k_gemm(const float* __restrict__ A,
                                              const float* __restrict__ W,
                                              const float* __restrict__ bias,
                                              const float* __restrict__ resT,
                                              float* out) {
  __shared__ float smem[BM * (BN + 1)];
  float(*As)[BM] = (float(*)[BM])smem;
  float(*Bs)[BN] = (float(*)[BN])(smem + BK * BM);

  int tid = threadIdx.x;
  int tx = tid & 15, ty = tid >> 4;
  int n0 = blockIdx.x * BN;
  int m0 = blockIdx.y * BM;
  int b = m0 >> 10, t0 = m0 & (LL - 1);

  float acc[8][4];
#pragma unroll
  for (int i = 0; i < 8; ++i)
#pragma unroll
    for (int j = 0; j < 4; ++j) acc[i][j] = 0.f;

  for (int k0 = 0; k0 < DD; k0 += BK) {
    if (MODE == 1) {
      int k = tid >> 4, m8 = (tid & 15) * 8;
      const float* src = A + ((size_t)b * DD + k0 + k) * LL + t0 + m8;
      float4 v0 = *(const float4*)src;
      float4 v1 = *(const float4*)(src + 4);
      *(float4*)&As[k][m8] = v0;
      *(float4*)&As[k][m8 + 4] = v1;
    } else {
      int m = tid >> 1, kq = (tid & 1) * 8;
      const float* src = A + (size_t)(m0 + m) * DD + k0 + kq;
      float4 v0 = *(const float4*)src;
      float4 v1 = *(const float4*)(src + 4);
      As[kq + 0][m] = v0.x; As[kq + 1][m] = v0.y;
      As[kq + 2][m] = v0.z; As[kq + 3][m] = v0.w;
      As[kq + 4][m] = v1.x; As[kq + 5][m] = v1.y;
      As[kq + 6][m] = v1.z; As[kq + 7][m] = v1.w;
    }
    {
      int k = tid >> 4, n4 = (tid & 15) * 4;
      *(float4*)&Bs[k][n4] = *(const float4*)(W + (size_t)(k0 + k) * DD + n0 + n4);
    }
    __syncthreads();
#pragma unroll
    for (int kk = 0; kk < BK; ++kk) {
      float a[8], bb[4];
      *(float4*)&a[0] = *(const float4*)&As[kk][ty * 8];
      *(float4*)&a[4] = *(const float4*)&As[kk][ty * 8 + 4];
      *(float4*)&bb[0] = *(const float4*)&Bs[kk][tx * 4];
#pragma unroll
      for (int i = 0; i < 8; ++i)
#pragma unroll
        for (int j = 0; j < 4; ++j) acc[i][j] += a[i] * bb[j];
    }
    __syncthreads();
  }

  if (MODE == 0) {
    float(*Cs)[BN + 1] = (float(*)[BN + 1])smem;
#pragma unroll
    for (int j = 0; j < 4; ++j) {
      float bv = bias[n0 + tx * 4 + j];
#pragma unroll
      for (int i = 0; i < 8; ++i) Cs[ty * 8 + i][tx * 4 + j] = acc[i][j] + bv;
    }
    __syncthreads();
#pragma unroll
    for (int it = 0; it < 32; ++it) {
      int n = it * 2 + (tid >> 7);
      int m = tid & 127;
      out[((size_t)b * DD + n0 + n) * LL + t0 + m] = Cs[m][n];
    }
  } else {
    if (MODE == 2) {
      float(*Xs)[BN + 1] = (float(*)[BN + 1])smem;
#pragma unroll
      for (int it = 0; it < 32; ++it) {
        int n = it * 2 + (tid >> 7);
        int m = tid & 127;
        Xs[m][n] = resT[((size_t)b * DD + n0 + n) * LL + t0 + m];
      }
      __syncthreads();
#pragma unroll
      for (int i = 0; i < 8; ++i)
#pragma unroll
        for (int j = 0; j < 4; ++j) acc[i][j] += Xs[ty * 8 + i][tx * 4 + j];
    }
    float bv[4];
#pragma unroll
    for (int j = 0; j < 4; ++j) bv[j] = bias[n0 + tx * 4 + j];
#pragma unroll
    for (int i = 0; i < 8; ++i) {
      float4 v;
      v.x = acc[i][0] + bv[0];
      v.y = acc[i][1] + bv[1];
      v.z = acc[i][2] + bv[2];
      v.w = acc[i][3] + bv[3];
      if (MODE == 1) {
        v.x = fmaxf(v.x, 0.f); v.y = fmaxf(v.y, 0.f);
        v.z = fmaxf(v.z, 0.f); v.w = fmaxf(v.w, 0.f);
      }
      *(float4*)&out[(size_t)(m0 + ty * 8 + i) * DD + n0 + tx * 4] = v;
    }
  }
}

// ================= autocorr + topk + softmax + aggregate + decomp1 =================
// one WG (256 thr, 4 waves) per (b, channel). QT may alias xsT (read-before-write).
// INJECTIVE quad-skew for K: phys(a) = a + 4*(a>>4) -- strictly monotone, so no
// write collisions; float4-contiguous within each 16-word group; hot-loop read
// stride becomes 20 words/lane -> 8-lane b128 phase covers all 32 banks once.
__global__ __launch_bounds__(256) void k_autocorr(const float* QT,
                                                  const float* __restrict__ KT,
                                                  const float* __restrict__ VT,
                                                  const float* __restrict__ xT,
                                                  float* xsT) {
  __shared__ float Qs[LL];
  __shared__ float Xs[LL];
  __shared__ float Vs2[2048];   // Vs2[p] = V[min(p,1023)] (saturating gather)
  __shared__ float Ks2[2560];   // K duplicated to 2048, skewed (max phys 2555)
  __shared__ float Cp[4][LL];   // corr partials; Cp[1..2] reused as padded series
  __shared__ float wvs[KTOP];
  __shared__ int wis[KTOP];

  int tid = threadIdx.x;
  int lane = tid & 63, wave = tid >> 6;
  size_t base = (size_t)blockIdx.x * LL;

  // ---- stage ----
  *(float4*)&Qs[tid * 4] = *(const float4*)(QT + base + tid * 4);
  *(float4*)&Xs[tid * 4] = *(const float4*)(xT + base + tid * 4);
  *(float4*)&Vs2[tid * 4] = *(const float4*)(VT + base + tid * 4);
#pragma unroll
  for (int qd = tid; qd < 512; qd += 256) {
    int a = qd * 4;
    float4 kv = *(const float4*)(KT + base + (a & (LL - 1)));
    int pa = a + ((a >> 4) << 2);
    *(float4*)&Ks2[pa] = kv;
  }
  __syncthreads();

  // ---- Corr[tau] = sum_t Q[t]*K[(t-tau) mod L], 16 taus/lane, quarter t per wave ----
  {
    int tau0 = lane * 16;
    float acc[16];
#pragma unroll
    for (int j = 0; j < 16; ++j) acc[j] = 0.f;
#pragma unroll 1
    for (int c = 0; c < 8; ++c) {
      int tb = wave * 256 + c * 32;
      int a0 = tb - tau0 - 16 + 1024;  // in [0,2000], mult of 4
      float kk[48];
#pragma unroll
      for (int qd = 0; qd < 12; ++qd) {
        int a = a0 + qd * 4;
        int pa = a + ((a >> 4) << 2);
        *(float4*)&kk[qd * 4] = *(const float4*)&Ks2[pa];
      }
#pragma unroll
      for (int s = 0; s < 4; ++s) {
        float q[8];
        *(float4*)&q[0] = *(const float4*)&Qs[tb + s * 8];
        *(float4*)&q[4] = *(const float4*)&Qs[tb + s * 8 + 4];
#pragma unroll
        for (int j = 0; j < 16; ++j) {
          float aj = acc[j];
#pragma unroll
          for (int i = 0; i < 8; ++i) aj += q[i] * kk[s * 8 + 16 + i - j];
          acc[j] = aj;
        }
      }
    }
#pragma unroll
    for (int qd = 0; qd < 4; ++qd)
      *(float4*)&Cp[wave][lane * 16 + qd * 4] = *(float4*)&acc[qd * 4];
  }
  __syncthreads();

  // ---- combine quarter partials into Cp[0] ----
  {
    float4 s0 = *(float4*)&Cp[0][tid * 4];
    float4 s1 = *(float4*)&Cp[1][tid * 4];
    float4 s2 = *(float4*)&Cp[2][tid * 4];
    float4 s3 = *(float4*)&Cp[3][tid * 4];
    s0.x += s1.x + s2.x + s3.x;
    s0.y += s1.y + s2.y + s3.y;
    s0.z += s1.z + s2.z + s3.z;
    s0.w += s1.w + s2.w + s3.w;
    *(float4*)&Cp[0][tid * 4] = s0;
  }
  __syncthreads();

  float* Csp = &Cp[1][0];  // padded series buffer [1056], aliases Cp[1..2]

  // ---- wave 0: register-resident top-20 + softmax; waves 1-3: fill Vs2 tail/pads ----
  if (wave == 0) {
    float c0[16];
#pragma unroll
    for (int qd = 0; qd < 4; ++qd)
      *(float4*)&c0[qd * 4] = *(const float4*)&Cp[0][lane * 16 + qd * 4];
    float lbest = c0[0];
    int lidx = 0;
#pragma unroll
    for (int m = 1; m < 16; ++m)
      if (c0[m] > lbest) { lbest = c0[m]; lidx = m; }

    float wv[KTOP];
    int wiR[KTOP];
#pragma unroll
    for (int sel = 0; sel < KTOP; ++sel) {
      float best = lbest;
      int bidx = lane * 16 + lidx;
#pragma unroll
      for (int off = 32; off; off >>= 1) {
        float v2 = __shfl_xor(best, off);
        int i2 = __shfl_xor(bidx, off);
        if (v2 > best || (v2 == best && i2 < bidx)) { best = v2; bidx = i2; }
      }
      wv[sel] = best;
      wiR[sel] = bidx;
      int kill = ((bidx >> 4) == lane) ? (bidx & 15) : -1;
#pragma unroll
      for (int m = 0; m < 16; ++m)
        if (m == kill) c0[m] = -3.0e38f;
      lbest = c0[0];
      lidx = 0;
#pragma unroll
      for (int m = 1; m < 16; ++m)
        if (c0[m] > lbest) { lbest = c0[m]; lidx = m; }
    }
    // softmax (every lane has identical wv/wiR)
    float mx = wv[0];
#pragma unroll
    for (int m = 1; m < KTOP; ++m) mx = fmaxf(mx, wv[m]);
    float ssum = 0.f;
#pragma unroll
    for (int m = 0; m < KTOP; ++m) {
      wv[m] = __expf(wv[m] - mx);
      ssum += wv[m];
    }
    float inv = 1.f / ssum;
    if (lane == 0) {
#pragma unroll
      for (int m = 0; m < KTOP; ++m) {
        wvs[m] = wv[m] * inv;
        wis[m] = wiR[m];
      }
    }
  } else {
    float vlast = Vs2[1023];
    for (int i = tid - 64; i < 1024; i += 192) Vs2[1024 + i] = vlast;
    if (tid >= 224 && tid < 240) Csp[tid - 224] = 0.f;        // front pad
    if (tid >= 240) Csp[1040 + (tid - 240)] = 0.f;            // back pad
  }
  __syncthreads();

  // ---- aggregate (saturating shift) + residual -> padded series ----
#pragma unroll
  for (int i = 0; i < 4; ++i) {
    int t = tid + 256 * i;
    float r = 0.f;
#pragma unroll
    for (int k = 0; k < KTOP; ++k) r += wvs[k] * Vs2[wis[k] + t];
    Csp[16 + t] = r + Xs[t];
  }
  __syncthreads();

  // ---- series_decomp #1 (count_include_pad): blocked 4 t/thread, sliding sum ----
  {
    int t0 = tid * 4;
    float buf[28];
#pragma unroll
    for (int qd = 0; qd < 7; ++qd)
      *(float4*)&buf[qd * 4] = *(const float4*)&Csp[t0 + 4 + qd * 4];
    float s = 0.f;
#pragma unroll
    for (int m = 0; m < 25; ++m) s += buf[m];
    float4 o;
    o.x = buf[12] - s * (1.0f / 25.0f);
    s += buf[25] - buf[0];
    o.y = buf[13] - s * (1.0f / 25.0f);
    s += buf[26] - buf[1];
    o.z = buf[14] - s * (1.0f / 25.0f);
    s += buf[27] - buf[2];
    o.w = buf[15] - s * (1.0f / 25.0f);
    *(float4*)&xsT[base + t0] = o;
  }
}

// ================= final series_decomp on s2 [B,L,D] (token-major) =================
#define TCH 64
__global__ __launch_bounds__(256) void k_decomp2(const float* __restrict__ s2,
                                                 float* __restrict__ out) {
  int b = blockIdx.z;
  int c = blockIdx.y * 256 + threadIdx.x;
  int t0 = blockIdx.x * TCH;
  const float* p = s2 + (size_t)b * LL * DD + c;
  float* o = out + (size_t)b * LL * DD + c;
  float wsum = 0.f;
  int lo = t0 - 12; lo = lo < 0 ? 0 : lo;
  int hi = t0 + 12; hi = hi > LL - 1 ? LL - 1 : hi;
  for (int j = lo; j <= hi; ++j) wsum += p[(size_t)j * DD];
  for (int t = t0; t < t0 + TCH; ++t) {
    float center = p[(size_t)t * DD];
    o[(size_t)t * DD] = center - wsum / 25.0f;
    float addv = (t + 13 < LL) ? p[(size_t)(t + 13) * DD] : 0.f;
    float subv = (t - 12 >= 0) ? p[(size_t)(t - 12) * DD] : 0.f;
    wsum += addv - subv;
  }
}

// ================= launch =================
extern "C" void kernel_launch(void* const* d_in, const int* in_sizes, int n_in,
                              void* d_out, int out_size, void* d_ws, size_t ws_size,
                              hipStream_t stream) {
  const float* x  = (const float*)d_in[0];
  const float* Wq = (const float*)d_in[1];
  const float* bq = (const float*)d_in[2];
  const float* Wk = (const float*)d_in[3];
  const float* bk = (const float*)d_in[4];
  const float* Wv = (const float*)d_in[5];
  const float* bv = (const float*)d_in[6];
  const float* W1 = (const float*)d_in[7];
  const float* b1 = (const float*)d_in[8];
  const float* W2 = (const float*)d_in[9];
  const float* b2 = (const float*)d_in[10];
  float* out = (float*)d_out;
  float* ws = (float*)d_ws;

  const size_t SZ = (size_t)NB * DD * LL;
  float* xT  = ws;
  float* QT  = ws + SZ;
  float* KT  = ws + 2 * SZ;
  float* VT  = ws + 3 * SZ;
  float* xsT = QT;
  float* h1  = xT;
  float* s2  = KT;

  k_transpose<<<dim3(16, 8, NB), 256, 0, stream>>>(x, xT);

  k_gemm<0><<<dim3(8, 64), 256, 0, stream>>>(x, Wq, bq, nullptr, QT);
  k_gemm<0><<<dim3(8, 64), 256, 0, stream>>>(x, Wk, bk, nullptr, KT);
  k_gemm<0><<<dim3(8, 64), 256, 0, stream>>>(x, Wv, bv, nullptr, VT);

  k_autocorr<<<dim3(NB * DD), 256, 0, stream>>>(QT, KT, VT, xT, xsT);

  k_gemm<1><<<dim3(8, 64), 256, 0, stream>>>(xsT, W1, b1, nullptr, h1);
  k_gemm<2><<<dim3(8, 64), 256, 0, stream>>>(h1, W2, b2, xsT, s2);

  k_decomp2<<<dim3(LL / TCH, DD / 256, NB), 256, 0, stream>>>(s2, out);
}

// Round 4
// 250.034 us; speedup vs baseline: 2.4109x; 2.1816x over previous
//
#include <hip/hip_runtime.h>
#include <math.h>

#define LL 1024
#define DD 512
#define NB 8
#define KTOP 20
#define SZ (8 * 512 * 1024)  // elems per [B,D,L] plane

typedef __attribute__((ext_vector_type(8))) short bf16x8;
typedef __attribute__((ext_vector_type(4))) float f32x4;
typedef __attribute__((ext_vector_type(4))) int i32x4;

__device__ __forceinline__ unsigned short f2bf(float f) {
  union { float f; unsigned u; } v; v.f = f;
  unsigned r = v.u + 0x7FFFu + ((v.u >> 16) & 1u);
  return (unsigned short)(r >> 16);
}
__device__ __forceinline__ float bf2f(unsigned short u) {
  union { unsigned u; float f; } v; v.u = ((unsigned)u) << 16;
  return v.f;
}

// ================= transpose x [B,L,D] -> xT [B,D,L] (f32) =================
__global__ __launch_bounds__(256) void k_transpose(const float* __restrict__ x,
                                                   float* __restrict__ xT) {
  __shared__ float T[64][65];
  int b = blockIdx.z;
  int t0 = blockIdx.x * 64, c0 = blockIdx.y * 64;
  int tid = threadIdx.x;
  int lane = tid & 63, row4 = tid >> 6;
#pragma unroll
  for (int it = 0; it < 16; ++it) {
    int tl = it * 4 + row4;
    T[lane][tl] = x[((size_t)b * LL + t0 + tl) * DD + c0 + lane];
  }
  __syncthreads();
#pragma unroll
  for (int it = 0; it < 16; ++it) {
    int cl = it * 4 + row4;
    xT[((size_t)b * DD + c0 + cl) * LL + t0 + lane] = T[cl][lane];
  }
}

// ================= pack W [512k][512n] f32 -> dst [n][k] bf16 =================
__global__ __launch_bounds__(256) void k_packw(const float* __restrict__ W,
                                               unsigned short* __restrict__ dst) {
  __shared__ float T[64][65];  // T[n][k]
  int k0 = blockIdx.x * 64, n0 = blockIdx.y * 64;
  int tid = threadIdx.x;
  int lane = tid & 63, r4 = tid >> 6;
#pragma unroll
  for (int it = 0; it < 16; ++it) {
    int kl = it * 4 + r4;
    T[lane][kl] = W[(size_t)(k0 + kl) * DD + n0 + lane];
  }
  __syncthreads();
  int n = tid >> 2, kq = (tid & 3) * 16;
  unsigned short* d = dst + (size_t)(n0 + n) * DD + k0 + kq;
#pragma unroll
  for (int j = 0; j < 16; j += 4) {
    ushort4 u;
    u.x = f2bf(T[n][kq + j]);
    u.y = f2bf(T[n][kq + j + 1]);
    u.z = f2bf(T[n][kq + j + 2]);
    u.w = f2bf(T[n][kq + j + 3]);
    *(ushort4*)&d[j] = u;
  }
}

__global__ __launch_bounds__(256) void k_packb(const float* __restrict__ bq,
                                               const float* __restrict__ bk,
                                               const float* __restrict__ bv,
                                               float* __restrict__ dst) {
  int i = blockIdx.x * 256 + threadIdx.x;  // 0..1535
  const float* s = (i < 512) ? bq : (i < 1024) ? bk : bv;
  dst[i] = s[i & 511];
}

// ================= MFMA GEMM: C[M,N] = A[M,512] @ B^T[N,512], 128x128 tile =====
// MODE 0: bias; out bf16 chan-major (n<1024: Q/K) or f32 chan-major (n>=1024: V)
// MODE 1: bias+relu; out bf16 token-major (h1)
// MODE 2: bias+residual(resbT bf16 chan-major); out f32 chan-major (s2T)
template <int MODE, bool AF32>
__global__ __launch_bounds__(256) void k_mfma(const void* __restrict__ Aptr,
                                              const unsigned short* __restrict__ Bt,
                                              const float* __restrict__ bias,
                                              const unsigned short* __restrict__ resbT,
                                              unsigned short* __restrict__ outU,
                                              float* __restrict__ outF, int gx) {
  __shared__ char smem[34816];
  unsigned short* As = (unsigned short*)smem;            // [128][64] quad-swizzled
  unsigned short* Bs = (unsigned short*)(smem + 16384);
  float* Cs = (float*)smem;

  int tid = threadIdx.x;
  int lane = tid & 63, wid = tid >> 6;
  int wr = wid & 1, wc = wid >> 1;

  // XCD-bijective swizzle (grid % 8 == 0)
  int nwg = gridDim.x;
  int wg = blockIdx.x;
  int swz = (wg & 7) * (nwg >> 3) + (wg >> 3);
  int bix = swz % gx, biy = swz / gx;
  int n0 = bix * 128, m0 = biy * 128;
  int b = m0 >> 10, t0 = m0 & (LL - 1);

  f32x4 acc[4][4];
#pragma unroll
  for (int i = 0; i < 4; ++i)
#pragma unroll
    for (int j = 0; j < 4; ++j) acc[i][j] = (f32x4){0.f, 0.f, 0.f, 0.f};

  int srow = tid >> 3, sq = tid & 7;

  for (int k0 = 0; k0 < 512; k0 += 64) {
#pragma unroll
    for (int p = 0; p < 4; ++p) {
      int r = srow + p * 32;
      int dq = sq ^ (r & 7);
      if (AF32) {
        const float* s = (const float*)Aptr + (size_t)(m0 + r) * 512 + k0 + sq * 8;
        float4 v0 = *(const float4*)s;
        float4 v1 = *(const float4*)(s + 4);
        unsigned short tmp[8];
        tmp[0] = f2bf(v0.x); tmp[1] = f2bf(v0.y); tmp[2] = f2bf(v0.z); tmp[3] = f2bf(v0.w);
        tmp[4] = f2bf(v1.x); tmp[5] = f2bf(v1.y); tmp[6] = f2bf(v1.z); tmp[7] = f2bf(v1.w);
        *(i32x4*)&As[r * 64 + dq * 8] = *(const i32x4*)tmp;
      } else {
        *(i32x4*)&As[r * 64 + dq * 8] =
            *(const i32x4*)((const unsigned short*)Aptr + (size_t)(m0 + r) * 512 + k0 + sq * 8);
      }
      *(i32x4*)&Bs[r * 64 + dq * 8] =
          *(const i32x4*)(Bt + (size_t)(n0 + r) * 512 + k0 + sq * 8);
    }
    __syncthreads();
#pragma unroll
    for (int ks = 0; ks < 2; ++ks) {
      bf16x8 af[4], bf[4];
      int fr = lane & 15, kq = lane >> 4;
#pragma unroll
      for (int mi = 0; mi < 4; ++mi) {
        int r = wr * 64 + mi * 16 + fr;
        af[mi] = *(bf16x8*)&As[r * 64 + ((ks * 4 + kq) ^ (r & 7)) * 8];
      }
#pragma unroll
      for (int ni = 0; ni < 4; ++ni) {
        int r = wc * 64 + ni * 16 + fr;
        bf[ni] = *(bf16x8*)&Bs[r * 64 + ((ks * 4 + kq) ^ (r & 7)) * 8];
      }
#pragma unroll
      for (int mi = 0; mi < 4; ++mi)
#pragma unroll
        for (int ni = 0; ni < 4; ++ni)
          acc[mi][ni] = __builtin_amdgcn_mfma_f32_16x16x32_bf16(af[mi], bf[ni], acc[mi][ni], 0, 0, 0);
    }
    __syncthreads();
  }

  if (MODE == 0 || MODE == 2) {
    const int LDc = 132;  // 128 m + 4 pad (f32 words)
    for (int p = 0; p < 2; ++p) {
      __syncthreads();
      if (MODE == 2) {
        int n = tid >> 2, mq = tid & 3;
        const unsigned short* rrow =
            resbT + ((size_t)(b * 512) + n0 + p * 64 + n) * LL + t0;
#pragma unroll
        for (int i = 0; i < 8; ++i) {
          int m = mq * 4 + i * 16;
          ushort4 u = *(const ushort4*)&rrow[m];
          float4 v;
          v.x = bf2f(u.x); v.y = bf2f(u.y); v.z = bf2f(u.z); v.w = bf2f(u.w);
          *(float4*)&Cs[n * LDc + m] = v;
        }
        __syncthreads();
      }
      if (wc == p) {
#pragma unroll
        for (int mi = 0; mi < 4; ++mi)
#pragma unroll
          for (int ni = 0; ni < 4; ++ni) {
            int nl = ni * 16 + (lane & 15);
            int ml = wr * 64 + mi * 16 + (lane >> 4) * 4;
            if (MODE == 2) {
              f32x4 cur = *(f32x4*)&Cs[nl * LDc + ml];
              cur += acc[mi][ni];
              *(f32x4*)&Cs[nl * LDc + ml] = cur;
            } else {
              *(f32x4*)&Cs[nl * LDc + ml] = acc[mi][ni];
            }
          }
      }
      __syncthreads();
      {
        int n = tid >> 2, mq = tid & 3;
        int ng = n0 + p * 64 + n;
        float bv = bias[ng];
        if (MODE == 0 && ng < 1024) {
          int sel = ng >> 9;
          unsigned short* drow =
              outU + ((size_t)sel * NB * 512 + b * 512 + (ng & 511)) * LL + t0;
#pragma unroll
          for (int i = 0; i < 8; ++i) {
            int m = mq * 4 + i * 16;
            float4 v = *(float4*)&Cs[n * LDc + m];
            ushort4 u;
            u.x = f2bf(v.x + bv); u.y = f2bf(v.y + bv);
            u.z = f2bf(v.z + bv); u.w = f2bf(v.w + bv);
            *(ushort4*)&drow[m] = u;
          }
        } else {
          int cch = (MODE == 0) ? (ng - 1024) : ng;
          float* drow = outF + ((size_t)b * 512 + cch) * LL + t0;
#pragma unroll
          for (int i = 0; i < 8; ++i) {
            int m = mq * 4 + i * 16;
            float4 v = *(float4*)&Cs[n * LDc + m];
            v.x += bv; v.y += bv; v.z += bv; v.w += bv;
            *(float4*)&drow[m] = v;
          }
        }
      }
    }
  } else {  // MODE 1: token-major bf16 + relu
    const int LDh = 68;
    for (int p = 0; p < 2; ++p) {
      __syncthreads();
      if (wc == p) {
#pragma unroll
        for (int mi = 0; mi < 4; ++mi)
#pragma unroll
          for (int ni = 0; ni < 4; ++ni) {
            int nl = ni * 16 + (lane & 15);
            int ml = wr * 64 + mi * 16 + (lane >> 4) * 4;
#pragma unroll
            for (int r = 0; r < 4; ++r) Cs[(ml + r) * LDh + nl] = acc[mi][ni][r];
          }
      }
      __syncthreads();
      {
        int m = tid >> 1, nh = tid & 1;
        unsigned short* drow =
            outU + (size_t)(m0 + m) * 512 + n0 + p * 64 + nh * 32;
#pragma unroll
        for (int c = 0; c < 8; ++c) {
          float4 v = *(float4*)&Cs[m * LDh + nh * 32 + c * 4];
          float4 bb = *(const float4*)&bias[n0 + p * 64 + nh * 32 + c * 4];
          v.x = fmaxf(v.x + bb.x, 0.f);
          v.y = fmaxf(v.y + bb.y, 0.f);
          v.z = fmaxf(v.z + bb.z, 0.f);
          v.w = fmaxf(v.w + bb.w, 0.f);
          ushort4 u;
          u.x = f2bf(v.x); u.y = f2bf(v.y); u.z = f2bf(v.z); u.w = f2bf(v.w);
          *(ushort4*)&drow[c * 4] = u;
        }
      }
    }
  }
}

// ================= autocorr + topk + softmax + aggregate + decomp1 =================
// one WG (4 waves) per (b,channel). Q/K bf16 in, xs bf16 chan-major out (in-place
// over Q row). Ks2 skew phys(a)=a+4*(a>>4) (injective). Cp quad-swizzle kills the
// stride-16 bank conflicts: CPIDX(i) = i ^ (((i>>5)&3)<<2).
#define CPIDX(i) ((i) ^ ((((i) >> 5) & 3) << 2))
__global__ __launch_bounds__(256) void k_autocorr(const unsigned short* __restrict__ Qbf,
                                                  const unsigned short* __restrict__ Kbf,
                                                  const float* __restrict__ Vf,
                                                  const float* __restrict__ xT,
                                                  unsigned short* __restrict__ xsbT) {
  __shared__ float Qs[LL];
  __shared__ float Xs[LL];
  __shared__ float Vs2[2048];
  __shared__ float Ks2[2560];
  __shared__ float Cp[2][1056];  // Cp[1] reused as padded series (1056)
  __shared__ float wvs[KTOP];
  __shared__ int wis[KTOP];

  int tid = threadIdx.x;
  int lane = tid & 63, wave = tid >> 6;
  size_t base = (size_t)blockIdx.x * LL;

  // ---- stage (Q,K bf16 -> f32) ----
  {
    ushort4 q = *(const ushort4*)(Qbf + base + tid * 4);
    float4 qf; qf.x = bf2f(q.x); qf.y = bf2f(q.y); qf.z = bf2f(q.z); qf.w = bf2f(q.w);
    *(float4*)&Qs[tid * 4] = qf;
    *(float4*)&Xs[tid * 4] = *(const float4*)(xT + base + tid * 4);
    *(float4*)&Vs2[tid * 4] = *(const float4*)(Vf + base + tid * 4);
  }
#pragma unroll
  for (int qd = tid; qd < 512; qd += 256) {
    int a = qd * 4;
    ushort4 k = *(const ushort4*)(Kbf + base + (a & (LL - 1)));
    float4 kf; kf.x = bf2f(k.x); kf.y = bf2f(k.y); kf.z = bf2f(k.z); kf.w = bf2f(k.w);
    int pa = a + ((a >> 4) << 2);
    *(float4*)&Ks2[pa] = kf;
  }
  __syncthreads();

  // ---- Corr[tau] = sum_t Q[t]*K[(t-tau) mod L] ----
  float acc[16];
  {
    int tau0 = lane * 16;
#pragma unroll
    for (int j = 0; j < 16; ++j) acc[j] = 0.f;
#pragma unroll 1
    for (int c = 0; c < 8; ++c) {
      int tb = wave * 256 + c * 32;
      int a0 = tb - tau0 - 16 + 1024;
      float kk[48];
#pragma unroll
      for (int qd = 0; qd < 12; ++qd) {
        int a = a0 + qd * 4;
        int pa = a + ((a >> 4) << 2);
        *(float4*)&kk[qd * 4] = *(const float4*)&Ks2[pa];
      }
#pragma unroll
      for (int s = 0; s < 4; ++s) {
        float q[8];
        *(float4*)&q[0] = *(const float4*)&Qs[tb + s * 8];
        *(float4*)&q[4] = *(const float4*)&Qs[tb + s * 8 + 4];
#pragma unroll
        for (int j = 0; j < 16; ++j) {
          float aj = acc[j];
#pragma unroll
          for (int i = 0; i < 8; ++i) aj += q[i] * kk[s * 8 + 16 + i - j];
          acc[j] = aj;
        }
      }
    }
  }
  // ---- phased accumulate into Cp[0..1] (swizzled) ----
  __syncthreads();
  if (wave < 2) {
#pragma unroll
    for (int qd = 0; qd < 4; ++qd)
      *(float4*)&Cp[wave][CPIDX(lane * 16 + qd * 4)] = *(float4*)&acc[qd * 4];
  }
  __syncthreads();
  if (wave >= 2) {
#pragma unroll
    for (int qd = 0; qd < 4; ++qd) {
      int ix = CPIDX(lane * 16 + qd * 4);
      float4 c = *(float4*)&Cp[wave - 2][ix];
      c.x += acc[qd * 4]; c.y += acc[qd * 4 + 1];
      c.z += acc[qd * 4 + 2]; c.w += acc[qd * 4 + 3];
      *(float4*)&Cp[wave - 2][ix] = c;
    }
  }
  __syncthreads();
  {
    int ix = CPIDX(tid * 4);
    float4 a = *(float4*)&Cp[0][ix];
    float4 bb = *(float4*)&Cp[1][ix];
    a.x += bb.x; a.y += bb.y; a.z += bb.z; a.w += bb.w;
    *(float4*)&Cp[0][ix] = a;
  }
  __syncthreads();

  float* Csp = &Cp[1][0];  // padded series [1056]

  // ---- wave 0: register top-20 + softmax; waves 1-3: Vs2 tail + pads ----
  if (wave == 0) {
    float c0[16];
#pragma unroll
    for (int qd = 0; qd < 4; ++qd)
      *(float4*)&c0[qd * 4] = *(const float4*)&Cp[0][CPIDX(lane * 16 + qd * 4)];
    float lbest = c0[0];
    int lidx = 0;
#pragma unroll
    for (int m = 1; m < 16; ++m)
      if (c0[m] > lbest) { lbest = c0[m]; lidx = m; }

    float wv[KTOP];
    int wiR[KTOP];
#pragma unroll
    for (int sel = 0; sel < KTOP; ++sel) {
      float best = lbest;
      int bidx = lane * 16 + lidx;
#pragma unroll
      for (int off = 32; off; off >>= 1) {
        float v2 = __shfl_xor(best, off);
        int i2 = __shfl_xor(bidx, off);
        if (v2 > best || (v2 == best && i2 < bidx)) { best = v2; bidx = i2; }
      }
      wv[sel] = best;
      wiR[sel] = bidx;
      int kill = ((bidx >> 4) == lane) ? (bidx & 15) : -1;
#pragma unroll
      for (int m = 0; m < 16; ++m)
        if (m == kill) c0[m] = -3.0e38f;
      lbest = c0[0];
      lidx = 0;
#pragma unroll
      for (int m = 1; m < 16; ++m)
        if (c0[m] > lbest) { lbest = c0[m]; lidx = m; }
    }
    float mx = wv[0];
#pragma unroll
    for (int m = 1; m < KTOP; ++m) mx = fmaxf(mx, wv[m]);
    float ssum = 0.f;
#pragma unroll
    for (int m = 0; m < KTOP; ++m) {
      wv[m] = __expf(wv[m] - mx);
      ssum += wv[m];
    }
    float inv = 1.f / ssum;
    if (lane == 0) {
#pragma unroll
      for (int m = 0; m < KTOP; ++m) {
        wvs[m] = wv[m] * inv;
        wis[m] = wiR[m];
      }
    }
  } else {
    float vlast = Vs2[1023];
    for (int i = tid - 64; i < 1024; i += 192) Vs2[1024 + i] = vlast;
    if (tid >= 224 && tid < 240) Csp[tid - 224] = 0.f;
    if (tid >= 240) Csp[1040 + (tid - 240)] = 0.f;
  }
  __syncthreads();

  // ---- aggregate (saturating shift) + residual ----
#pragma unroll
  for (int i = 0; i < 4; ++i) {
    int t = tid + 256 * i;
    float r = 0.f;
#pragma unroll
    for (int k = 0; k < KTOP; ++k) r += wvs[k] * Vs2[wis[k] + t];
    Csp[16 + t] = r + Xs[t];
  }
  __syncthreads();

  // ---- series_decomp #1 -> bf16 chan-major ----
  {
    int t0 = tid * 4;
    float buf[28];
#pragma unroll
    for (int qd = 0; qd < 7; ++qd)
      *(float4*)&buf[qd * 4] = *(const float4*)&Csp[t0 + 4 + qd * 4];
    float s = 0.f;
#pragma unroll
    for (int m = 0; m < 25; ++m) s += buf[m];
    ushort4 o;
    o.x = f2bf(buf[12] - s * (1.0f / 25.0f));
    s += buf[25] - buf[0];
    o.y = f2bf(buf[13] - s * (1.0f / 25.0f));
    s += buf[26] - buf[1];
    o.z = f2bf(buf[14] - s * (1.0f / 25.0f));
    s += buf[27] - buf[2];
    o.w = f2bf(buf[15] - s * (1.0f / 25.0f));
    *(ushort4*)&xsbT[base + t0] = o;
  }
}

// ================= xsbT [c][t] bf16 -> xsb [t][c] bf16 =================
__global__ __launch_bounds__(256) void k_castT(const unsigned short* __restrict__ src,
                                               unsigned short* __restrict__ dst) {
  __shared__ unsigned short T[64][68];
  int b = blockIdx.z;
  int t0 = blockIdx.x * 64, c0 = blockIdx.y * 64;
  int tid = threadIdx.x;
  int lane = tid & 63, r4 = tid >> 6;
#pragma unroll
  for (int it = 0; it < 16; ++it) {
    int cl = it * 4 + r4;
    T[lane][cl] = src[((size_t)b * 512 + c0 + cl) * LL + t0 + lane];
  }
  __syncthreads();
  int tl = tid >> 2, cq = (tid & 3) * 16;
  unsigned short* d = dst + ((size_t)b * LL + t0 + tl) * 512 + c0 + cq;
#pragma unroll
  for (int j = 0; j < 16; j += 4) {
    ushort4 u;
    u.x = T[tl][cq + j]; u.y = T[tl][cq + j + 1];
    u.z = T[tl][cq + j + 2]; u.w = T[tl][cq + j + 3];
    *(ushort4*)&d[j] = u;
  }
}

// ================= final decomp: s2T [c][t] f32 -> out [t][c] f32 =================
#define DCH 32
__global__ __launch_bounds__(256) void k_decomp2T(const float* __restrict__ s2T,
                                                  float* __restrict__ out) {
  __shared__ float T[DCH][289];
  int b = blockIdx.z, c0 = blockIdx.y * DCH, t0 = blockIdx.x * 256;
  int tid = threadIdx.x;
  {
    int row = tid >> 3, j0 = tid & 7;
    const float* src = s2T + ((size_t)b * 512 + c0 + row) * LL;
#pragma unroll
    for (int i = 0; i < 9; ++i) {
      int col = (j0 + i * 8) * 4;
      int t = t0 - 16 + col;
      float4 v = make_float4(0.f, 0.f, 0.f, 0.f);
      if (t >= 0 && t < LL) v = *(const float4*)&src[t];
      *(float4*)&T[row][col] = v;
    }
  }
  __syncthreads();
  int c = tid & 31, tg = tid >> 5;
  float sum = 0.f;
  int basec = tg * 32 + 4;
#pragma unroll
  for (int j = 0; j < 25; ++j) sum += T[c][basec + j];
  float* orow = out + ((size_t)b * LL + t0 + tg * 32) * 512 + c0 + c;
#pragma unroll 1
  for (int s = 0; s < 32; ++s) {
    float center = T[c][tg * 32 + 16 + s];
    orow[(size_t)s * 512] = center - sum * (1.f / 25.f);
    sum += T[c][basec + 25 + s] - T[c][basec + s];
  }
}

// ================= launch =================
extern "C" void kernel_launch(void* const* d_in, const int* in_sizes, int n_in,
                              void* d_out, int out_size, void* d_ws, size_t ws_size,
                              hipStream_t stream) {
  const float* x  = (const float*)d_in[0];
  const float* Wq = (const float*)d_in[1];
  const float* bq = (const float*)d_in[2];
  const float* Wk = (const float*)d_in[3];
  const float* bk = (const float*)d_in[4];
  const float* Wv = (const float*)d_in[5];
  const float* bv = (const float*)d_in[6];
  const float* W1 = (const float*)d_in[7];
  const float* b1 = (const float*)d_in[8];
  const float* W2 = (const float*)d_in[9];
  const float* b2 = (const float*)d_in[10];
  float* out = (float*)d_out;
  char* w = (char*)d_ws;

  // layout (bytes): [0, 4SZ) xT f32  (later: h1 bf16 [0,2SZ) + xsb bf16 [2SZ,4SZ))
  //                 [4SZ, 6SZ) Q bf16 -> xsbT ;  [6SZ, 8SZ) K bf16
  //                 [8SZ, 12SZ) V f32 -> s2T ;   [12SZ, ..) packed weights
  float* xT            = (float*)w;
  unsigned short* Qbf  = (unsigned short*)(w + (size_t)SZ * 4);
  unsigned short* Kbf  = Qbf + SZ;
  float* Vf            = (float*)(w + (size_t)SZ * 8);
  unsigned short* WqkvT = (unsigned short*)(w + (size_t)SZ * 12);
  unsigned short* W1T  = WqkvT + 1536 * 512;
  unsigned short* W2T  = W1T + 512 * 512;
  float* bqkv          = (float*)(W2T + 512 * 512);
  unsigned short* h1   = (unsigned short*)w;
  unsigned short* xsb  = (unsigned short*)(w + (size_t)SZ * 2);
  unsigned short* xsbT = Qbf;
  float* s2T           = Vf;

  k_transpose<<<dim3(16, 8, NB), 256, 0, stream>>>(x, xT);
  k_packw<<<dim3(8, 8), 256, 0, stream>>>(Wq, WqkvT);
  k_packw<<<dim3(8, 8), 256, 0, stream>>>(Wk, WqkvT + 512 * 512);
  k_packw<<<dim3(8, 8), 256, 0, stream>>>(Wv, WqkvT + 1024 * 512);
  k_packw<<<dim3(8, 8), 256, 0, stream>>>(W1, W1T);
  k_packw<<<dim3(8, 8), 256, 0, stream>>>(W2, W2T);
  k_packb<<<dim3(6), 256, 0, stream>>>(bq, bk, bv, bqkv);

  k_mfma<0, true><<<dim3(768), 256, 0, stream>>>(x, WqkvT, bqkv, nullptr, Qbf, Vf, 12);

  k_autocorr<<<dim3(NB * DD), 256, 0, stream>>>(Qbf, Kbf, Vf, xT, xsbT);

  k_castT<<<dim3(16, 8, NB), 256, 0, stream>>>(xsbT, xsb);

  k_mfma<1, false><<<dim3(256), 256, 0, stream>>>(xsb, W1T, b1, nullptr, h1, nullptr, 4);
  k_mfma<2, false><<<dim3(256), 256, 0, stream>>>(h1, W2T, b2, xsbT, nullptr, s2T, 4);

  k_decomp2T<<<dim3(4, 16, NB), 256, 0, stream>>>(s2T, out);
}

// Round 5
// 210.694 us; speedup vs baseline: 2.8610x; 1.1867x over previous
//
#include <hip/hip_runtime.h>
#include <math.h>

#define LL 1024
#define DD 512
#define NB 8
#define KTOP 20
#define SZ (8 * 512 * 1024)  // elems per [B,D,L] plane

typedef __attribute__((ext_vector_type(8))) short bf16x8;
typedef __attribute__((ext_vector_type(4))) float f32x4;
typedef __attribute__((ext_vector_type(4))) int i32x4;

__device__ __forceinline__ unsigned short f2bf(float f) {
  union { float f; unsigned u; } v; v.f = f;
  unsigned r = v.u + 0x7FFFu + ((v.u >> 16) & 1u);
  return (unsigned short)(r >> 16);
}
__device__ __forceinline__ float bf2f(unsigned short u) {
  union { unsigned u; float f; } v; v.u = ((unsigned)u) << 16;
  return v.f;
}

// ================= transpose x [B,L,D] -> xT [B,D,L] (f32) =================
__global__ __launch_bounds__(256) void k_transpose(const float* __restrict__ x,
                                                   float* __restrict__ xT) {
  __shared__ float T[64][65];
  int b = blockIdx.z;
  int t0 = blockIdx.x * 64, c0 = blockIdx.y * 64;
  int tid = threadIdx.x;
  int lane = tid & 63, row4 = tid >> 6;
#pragma unroll
  for (int it = 0; it < 16; ++it) {
    int tl = it * 4 + row4;
    T[lane][tl] = x[((size_t)b * LL + t0 + tl) * DD + c0 + lane];
  }
  __syncthreads();
#pragma unroll
  for (int it = 0; it < 16; ++it) {
    int cl = it * 4 + row4;
    xT[((size_t)b * DD + c0 + cl) * LL + t0 + lane] = T[cl][lane];
  }
}

// ================= pack W [512k][512n] f32 -> dst [n][k] bf16 =================
__global__ __launch_bounds__(256) void k_packw(const float* __restrict__ W,
                                               unsigned short* __restrict__ dst) {
  __shared__ float T[64][65];  // T[n][k]
  int k0 = blockIdx.x * 64, n0 = blockIdx.y * 64;
  int tid = threadIdx.x;
  int lane = tid & 63, r4 = tid >> 6;
#pragma unroll
  for (int it = 0; it < 16; ++it) {
    int kl = it * 4 + r4;
    T[lane][kl] = W[(size_t)(k0 + kl) * DD + n0 + lane];
  }
  __syncthreads();
  int n = tid >> 2, kq = (tid & 3) * 16;
  unsigned short* d = dst + (size_t)(n0 + n) * DD + k0 + kq;
#pragma unroll
  for (int j = 0; j < 16; j += 4) {
    ushort4 u;
    u.x = f2bf(T[n][kq + j]);
    u.y = f2bf(T[n][kq + j + 1]);
    u.z = f2bf(T[n][kq + j + 2]);
    u.w = f2bf(T[n][kq + j + 3]);
    *(ushort4*)&d[j] = u;
  }
}

__global__ __launch_bounds__(256) void k_packb(const float* __restrict__ bq,
                                               const float* __restrict__ bk,
                                               const float* __restrict__ bv,
                                               float* __restrict__ dst) {
  int i = blockIdx.x * 256 + threadIdx.x;  // 0..1535
  const float* s = (i < 512) ? bq : (i < 1024) ? bk : bv;
  dst[i] = s[i & 511];
}

// ================= MFMA GEMM: C[M,N] = A[M,512] @ B^T[N,512], 128x128 tile =====
// MODE 0: bias; out bf16 chan-major (n<1024: Q/K) or f32 chan-major (n>=1024: V)
// MODE 1: bias+relu; out bf16 token-major (h1)
// MODE 2: bias+residual(resbT bf16 chan-major); out f32 chan-major (s2T)
template <int MODE, bool AF32>
__global__ __launch_bounds__(256) void k_mfma(const void* __restrict__ Aptr,
                                              const unsigned short* __restrict__ Bt,
                                              const float* __restrict__ bias,
                                              const unsigned short* __restrict__ resbT,
                                              unsigned short* __restrict__ outU,
                                              float* __restrict__ outF, int gx) {
  __shared__ char smem[34816];
  unsigned short* As = (unsigned short*)smem;            // [128][64] quad-swizzled
  unsigned short* Bs = (unsigned short*)(smem + 16384);
  float* Cs = (float*)smem;

  int tid = threadIdx.x;
  int lane = tid & 63, wid = tid >> 6;
  int wr = wid & 1, wc = wid >> 1;

  // XCD-bijective swizzle (grid % 8 == 0)
  int nwg = gridDim.x;
  int wg = blockIdx.x;
  int swz = (wg & 7) * (nwg >> 3) + (wg >> 3);
  int bix = swz % gx, biy = swz / gx;
  int n0 = bix * 128, m0 = biy * 128;
  int b = m0 >> 10, t0 = m0 & (LL - 1);

  f32x4 acc[4][4];
#pragma unroll
  for (int i = 0; i < 4; ++i)
#pragma unroll
    for (int j = 0; j < 4; ++j) acc[i][j] = (f32x4){0.f, 0.f, 0.f, 0.f};

  int srow = tid >> 3, sq = tid & 7;

  for (int k0 = 0; k0 < 512; k0 += 64) {
#pragma unroll
    for (int p = 0; p < 4; ++p) {
      int r = srow + p * 32;
      int dq = sq ^ (r & 7);
      if (AF32) {
        const float* s = (const float*)Aptr + (size_t)(m0 + r) * 512 + k0 + sq * 8;
        float4 v0 = *(const float4*)s;
        float4 v1 = *(const float4*)(s + 4);
        unsigned short tmp[8];
        tmp[0] = f2bf(v0.x); tmp[1] = f2bf(v0.y); tmp[2] = f2bf(v0.z); tmp[3] = f2bf(v0.w);
        tmp[4] = f2bf(v1.x); tmp[5] = f2bf(v1.y); tmp[6] = f2bf(v1.z); tmp[7] = f2bf(v1.w);
        *(i32x4*)&As[r * 64 + dq * 8] = *(const i32x4*)tmp;
      } else {
        *(i32x4*)&As[r * 64 + dq * 8] =
            *(const i32x4*)((const unsigned short*)Aptr + (size_t)(m0 + r) * 512 + k0 + sq * 8);
      }
      *(i32x4*)&Bs[r * 64 + dq * 8] =
          *(const i32x4*)(Bt + (size_t)(n0 + r) * 512 + k0 + sq * 8);
    }
    __syncthreads();
#pragma unroll
    for (int ks = 0; ks < 2; ++ks) {
      bf16x8 af[4], bf[4];
      int fr = lane & 15, kq = lane >> 4;
#pragma unroll
      for (int mi = 0; mi < 4; ++mi) {
        int r = wr * 64 + mi * 16 + fr;
        af[mi] = *(bf16x8*)&As[r * 64 + ((ks * 4 + kq) ^ (r & 7)) * 8];
      }
#pragma unroll
      for (int ni = 0; ni < 4; ++ni) {
        int r = wc * 64 + ni * 16 + fr;
        bf[ni] = *(bf16x8*)&Bs[r * 64 + ((ks * 4 + kq) ^ (r & 7)) * 8];
      }
#pragma unroll
      for (int mi = 0; mi < 4; ++mi)
#pragma unroll
        for (int ni = 0; ni < 4; ++ni)
          acc[mi][ni] = __builtin_amdgcn_mfma_f32_16x16x32_bf16(af[mi], bf[ni], acc[mi][ni], 0, 0, 0);
    }
    __syncthreads();
  }

  if (MODE == 0 || MODE == 2) {
    const int LDc = 132;  // 128 m + 4 pad (f32 words)
    for (int p = 0; p < 2; ++p) {
      __syncthreads();
      if (MODE == 2) {
        int n = tid >> 2, mq = tid & 3;
        const unsigned short* rrow =
            resbT + ((size_t)(b * 512) + n0 + p * 64 + n) * LL + t0;
#pragma unroll
        for (int i = 0; i < 8; ++i) {
          int m = mq * 4 + i * 16;
          ushort4 u = *(const ushort4*)&rrow[m];
          float4 v;
          v.x = bf2f(u.x); v.y = bf2f(u.y); v.z = bf2f(u.z); v.w = bf2f(u.w);
          *(float4*)&Cs[n * LDc + m] = v;
        }
        __syncthreads();
      }
      if (wc == p) {
#pragma unroll
        for (int mi = 0; mi < 4; ++mi)
#pragma unroll
          for (int ni = 0; ni < 4; ++ni) {
            int nl = ni * 16 + (lane & 15);
            int ml = wr * 64 + mi * 16 + (lane >> 4) * 4;
            if (MODE == 2) {
              f32x4 cur = *(f32x4*)&Cs[nl * LDc + ml];
              cur += acc[mi][ni];
              *(f32x4*)&Cs[nl * LDc + ml] = cur;
            } else {
              *(f32x4*)&Cs[nl * LDc + ml] = acc[mi][ni];
            }
          }
      }
      __syncthreads();
      {
        int n = tid >> 2, mq = tid & 3;
        int ng = n0 + p * 64 + n;
        float bv = bias[ng];
        if (MODE == 0 && ng < 1024) {
          int sel = ng >> 9;
          unsigned short* drow =
              outU + ((size_t)sel * NB * 512 + b * 512 + (ng & 511)) * LL + t0;
#pragma unroll
          for (int i = 0; i < 8; ++i) {
            int m = mq * 4 + i * 16;
            float4 v = *(float4*)&Cs[n * LDc + m];
            ushort4 u;
            u.x = f2bf(v.x + bv); u.y = f2bf(v.y + bv);
            u.z = f2bf(v.z + bv); u.w = f2bf(v.w + bv);
            *(ushort4*)&drow[m] = u;
          }
        } else {
          int cch = (MODE == 0) ? (ng - 1024) : ng;
          float* drow = outF + ((size_t)b * 512 + cch) * LL + t0;
#pragma unroll
          for (int i = 0; i < 8; ++i) {
            int m = mq * 4 + i * 16;
            float4 v = *(float4*)&Cs[n * LDc + m];
            v.x += bv; v.y += bv; v.z += bv; v.w += bv;
            *(float4*)&drow[m] = v;
          }
        }
      }
    }
  } else {  // MODE 1: token-major bf16 + relu
    const int LDh = 68;
    for (int p = 0; p < 2; ++p) {
      __syncthreads();
      if (wc == p) {
#pragma unroll
        for (int mi = 0; mi < 4; ++mi)
#pragma unroll
          for (int ni = 0; ni < 4; ++ni) {
            int nl = ni * 16 + (lane & 15);
            int ml = wr * 64 + mi * 16 + (lane >> 4) * 4;
#pragma unroll
            for (int r = 0; r < 4; ++r) Cs[(ml + r) * LDh + nl] = acc[mi][ni][r];
          }
      }
      __syncthreads();
      {
        int m = tid >> 1, nh = tid & 1;
        unsigned short* drow =
            outU + (size_t)(m0 + m) * 512 + n0 + p * 64 + nh * 32;
#pragma unroll
        for (int c = 0; c < 8; ++c) {
          float4 v = *(float4*)&Cs[m * LDh + nh * 32 + c * 4];
          float4 bb = *(const float4*)&bias[n0 + p * 64 + nh * 32 + c * 4];
          v.x = fmaxf(v.x + bb.x, 0.f);
          v.y = fmaxf(v.y + bb.y, 0.f);
          v.z = fmaxf(v.z + bb.z, 0.f);
          v.w = fmaxf(v.w + bb.w, 0.f);
          ushort4 u;
          u.x = f2bf(v.x); u.y = f2bf(v.y); u.z = f2bf(v.z); u.w = f2bf(v.w);
          *(ushort4*)&drow[c * 4] = u;
        }
      }
    }
  }
}

// ================= autocorr (MFMA) + topk + softmax + aggregate + decomp1 =====
// One WG (4 waves) per (b,channel). Corr via matrix cores:
//   tau = 256g + 16m + n ; C_g[m,n] = sum_k Q[(k+16m+256g)%L] * K[(k-n)%L]
// A_g frag: aligned reads from duplicated Q (shift multiple of 16 elems).
// B frag: Ksh[n][k] = bf16 K[(k-n)%L], 16 shifted rows built per k-half from
// f32 Kpre (4B reads handle the 2B-granular shift). Each wave owns one g.
__global__ __launch_bounds__(256) void k_autocorr(const unsigned short* __restrict__ Qbf,
                                                  const unsigned short* __restrict__ Kbf,
                                                  const float* __restrict__ Vf,
                                                  const float* __restrict__ xT,
                                                  unsigned short* __restrict__ xsbT) {
  __shared__ unsigned short Qs2[2048];     // Q duplicated (bf16)
  __shared__ unsigned short Ksh[16 * 520]; // 16 shifted K rows, half-K, +pad
  __shared__ float Vs2[2048];              // V + saturating tail
  __shared__ float Cp[1024];               // Corr
  __shared__ float Csp[1056];              // padded series; [0..1039] aliases Kpre
  __shared__ float wvs[KTOP];
  __shared__ int wis[KTOP];
  float* Kpre = Csp;  // f32 K with 16-elem circular prefix: Kpre[j]=K[(j-16)%L]

  int tid = threadIdx.x;
  int lane = tid & 63, wave = tid >> 6;
  size_t base = (size_t)blockIdx.x * LL;

  // ---- stage ----
  {
    ushort4 q = *(const ushort4*)(Qbf + base + tid * 4);
    *(ushort4*)&Qs2[tid * 4] = q;
    *(ushort4*)&Qs2[1024 + tid * 4] = q;
    *(float4*)&Vs2[tid * 4] = *(const float4*)(Vf + base + tid * 4);
    int j4 = tid * 4;
    int src = (j4 - 16) & (LL - 1);
    ushort4 k = *(const ushort4*)(Kbf + base + src);
    float4 kf;
    kf.x = bf2f(k.x); kf.y = bf2f(k.y); kf.z = bf2f(k.z); kf.w = bf2f(k.w);
    *(float4*)&Kpre[j4] = kf;
    if (tid < 4) {
      int j4b = 1024 + tid * 4;
      int srcb = (j4b - 16) & (LL - 1);
      ushort4 kb = *(const ushort4*)(Kbf + base + srcb);
      float4 kfb;
      kfb.x = bf2f(kb.x); kfb.y = bf2f(kb.y); kfb.z = bf2f(kb.z); kfb.w = bf2f(kb.w);
      *(float4*)&Kpre[j4b] = kfb;
    }
  }
  __syncthreads();

  // ---- correlation via MFMA, K split in two halves ----
  f32x4 acc = (f32x4){0.f, 0.f, 0.f, 0.f};
  int fr = lane & 15, kq = lane >> 4;
  int g = wave;
#pragma unroll 1
  for (int h = 0; h < 2; ++h) {
    // build Ksh[n][p] = bf16( K[(512h + p - n) % L] ), p in [0,512)
#pragma unroll
    for (int it = 0; it < 16; ++it) {
      int task = tid + 256 * it;     // 0..4095
      int n = task >> 8;             // 0..15 (wave-uniform per iteration)
      int p2 = (task & 255) * 2;     // even in [0,510]
      int sidx = 16 + 512 * h + p2 - n;  // >= 1
      float a0 = Kpre[sidx];
      float a1 = Kpre[sidx + 1];
      unsigned u = (unsigned)f2bf(a0) | ((unsigned)f2bf(a1) << 16);
      *(unsigned*)&Ksh[n * 520 + p2] = u;
    }
    __syncthreads();
#pragma unroll 4
    for (int ks = 0; ks < 16; ++ks) {
      bf16x8 av = *(const bf16x8*)&Qs2[512 * h + ks * 32 + kq * 8 + 16 * fr + 256 * g];
      bf16x8 bv = *(const bf16x8*)&Ksh[fr * 520 + ks * 32 + kq * 8];
      acc = __builtin_amdgcn_mfma_f32_16x16x32_bf16(av, bv, acc, 0, 0, 0);
    }
    __syncthreads();
  }
  // C layout: col(n)=lane&15, row(m)=(lane>>4)*4+r  -> tau = 256g + 16m + n
#pragma unroll
  for (int r = 0; r < 4; ++r) Cp[256 * g + 16 * (kq * 4 + r) + fr] = acc[r];
  __syncthreads();

  // ---- top-20 on wave 'sel' (spread across SIMDs); others fill Vs2 tail+pads --
  int sel = blockIdx.x & 3;
  if (wave == sel) {
    float c0[16];
#pragma unroll
    for (int qd = 0; qd < 4; ++qd)
      *(float4*)&c0[qd * 4] = *(const float4*)&Cp[lane * 16 + qd * 4];
    float lbest = c0[0];
    int lidx = 0;
#pragma unroll
    for (int m = 1; m < 16; ++m)
      if (c0[m] > lbest) { lbest = c0[m]; lidx = m; }

    float wv[KTOP];
    int wiR[KTOP];
#pragma unroll
    for (int s = 0; s < KTOP; ++s) {
      float best = lbest;
      int bidx = lane * 16 + lidx;
#pragma unroll
      for (int off = 32; off; off >>= 1) {
        float v2 = __shfl_xor(best, off);
        int i2 = __shfl_xor(bidx, off);
        if (v2 > best || (v2 == best && i2 < bidx)) { best = v2; bidx = i2; }
      }
      wv[s] = best;
      wiR[s] = bidx;
      int kill = ((bidx >> 4) == lane) ? (bidx & 15) : -1;
#pragma unroll
      for (int m = 0; m < 16; ++m)
        if (m == kill) c0[m] = -3.0e38f;
      lbest = c0[0];
      lidx = 0;
#pragma unroll
      for (int m = 1; m < 16; ++m)
        if (c0[m] > lbest) { lbest = c0[m]; lidx = m; }
    }
    float mx = wv[0];
#pragma unroll
    for (int m = 1; m < KTOP; ++m) mx = fmaxf(mx, wv[m]);
    float ssum = 0.f;
#pragma unroll
    for (int m = 0; m < KTOP; ++m) {
      wv[m] = __expf(wv[m] - mx);
      ssum += wv[m];
    }
    float inv = 1.f / ssum;
    if (lane == 0) {
#pragma unroll
      for (int m = 0; m < KTOP; ++m) {
        wvs[m] = wv[m] * inv;
        wis[m] = wiR[m];
      }
    }
  } else {
    float vlast = Vs2[1023];
    int ft = (wave < sel ? wave : wave - 1) * 64 + lane;  // 0..191
    for (int i = ft; i < 1024; i += 192) Vs2[1024 + i] = vlast;
    if (ft < 16) Csp[ft] = 0.f;                // front pad
    if (ft >= 16 && ft < 32) Csp[1040 + ft - 16] = 0.f;  // back pad
  }
  __syncthreads();

  // ---- aggregate (saturating shift) + residual -> padded series ----
  {
    int t0 = tid * 4;
    float4 xr = *(const float4*)(xT + base + t0);
    float r0 = xr.x, r1 = xr.y, r2 = xr.z, r3 = xr.w;
#pragma unroll
    for (int k = 0; k < KTOP; ++k) {
      float w = wvs[k];
      int wi = wis[k];
      r0 += w * Vs2[wi + t0];
      r1 += w * Vs2[wi + t0 + 1];
      r2 += w * Vs2[wi + t0 + 2];
      r3 += w * Vs2[wi + t0 + 3];
    }
    float4 rv;
    rv.x = r0; rv.y = r1; rv.z = r2; rv.w = r3;
    *(float4*)&Csp[16 + t0] = rv;
  }
  __syncthreads();

  // ---- series_decomp #1 -> bf16 chan-major ----
  {
    int t0 = tid * 4;
    float buf[28];
#pragma unroll
    for (int qd = 0; qd < 7; ++qd)
      *(float4*)&buf[qd * 4] = *(const float4*)&Csp[t0 + 4 + qd * 4];
    float s = 0.f;
#pragma unroll
    for (int m = 0; m < 25; ++m) s += buf[m];
    ushort4 o;
    o.x = f2bf(buf[12] - s * (1.0f / 25.0f));
    s += buf[25] - buf[0];
    o.y = f2bf(buf[13] - s * (1.0f / 25.0f));
    s += buf[26] - buf[1];
    o.z = f2bf(buf[14] - s * (1.0f / 25.0f));
    s += buf[27] - buf[2];
    o.w = f2bf(buf[15] - s * (1.0f / 25.0f));
    *(ushort4*)&xsbT[base + t0] = o;
  }
}

// ================= xsbT [c][t] bf16 -> xsb [t][c] bf16 =================
__global__ __launch_bounds__(256) void k_castT(const unsigned short* __restrict__ src,
                                               unsigned short* __restrict__ dst) {
  __shared__ unsigned short T[64][68];
  int b = blockIdx.z;
  int t0 = blockIdx.x * 64, c0 = blockIdx.y * 64;
  int tid = threadIdx.x;
  int lane = tid & 63, r4 = tid >> 6;
#pragma unroll
  for (int it = 0; it < 16; ++it) {
    int cl = it * 4 + r4;
    T[lane][cl] = src[((size_t)b * 512 + c0 + cl) * LL + t0 + lane];
  }
  __syncthreads();
  int tl = tid >> 2, cq = (tid & 3) * 16;
  unsigned short* d = dst + ((size_t)b * LL + t0 + tl) * 512 + c0 + cq;
#pragma unroll
  for (int j = 0; j < 16; j += 4) {
    ushort4 u;
    u.x = T[tl][cq + j]; u.y = T[tl][cq + j + 1];
    u.z = T[tl][cq + j + 2]; u.w = T[tl][cq + j + 3];
    *(ushort4*)&d[j] = u;
  }
}

// ================= final decomp: s2T [c][t] f32 -> out [t][c] f32 =================
#define DCH 32
__global__ __launch_bounds__(256) void k_decomp2T(const float* __restrict__ s2T,
                                                  float* __restrict__ out) {
  __shared__ float T[DCH][289];
  int b = blockIdx.z, c0 = blockIdx.y * DCH, t0 = blockIdx.x * 256;
  int tid = threadIdx.x;
  {
    int row = tid >> 3, j0 = tid & 7;
    const float* src = s2T + ((size_t)b * 512 + c0 + row) * LL;
#pragma unroll
    for (int i = 0; i < 9; ++i) {
      int col = (j0 + i * 8) * 4;
      int t = t0 - 16 + col;
      float4 v = make_float4(0.f, 0.f, 0.f, 0.f);
      if (t >= 0 && t < LL) v = *(const float4*)&src[t];
      *(float4*)&T[row][col] = v;
    }
  }
  __syncthreads();
  int c = tid & 31, tg = tid >> 5;
  float sum = 0.f;
  int basec = tg * 32 + 4;
#pragma unroll
  for (int j = 0; j < 25; ++j) sum += T[c][basec + j];
  float* orow = out + ((size_t)b * LL + t0 + tg * 32) * 512 + c0 + c;
#pragma unroll 1
  for (int s = 0; s < 32; ++s) {
    float center = T[c][tg * 32 + 16 + s];
    orow[(size_t)s * 512] = center - sum * (1.f / 25.f);
    sum += T[c][basec + 25 + s] - T[c][basec + s];
  }
}

// ================= launch =================
extern "C" void kernel_launch(void* const* d_in, const int* in_sizes, int n_in,
                              void* d_out, int out_size, void* d_ws, size_t ws_size,
                              hipStream_t stream) {
  const float* x  = (const float*)d_in[0];
  const float* Wq = (const float*)d_in[1];
  const float* bq = (const float*)d_in[2];
  const float* Wk = (const float*)d_in[3];
  const float* bk = (const float*)d_in[4];
  const float* Wv = (const float*)d_in[5];
  const float* bv = (const float*)d_in[6];
  const float* W1 = (const float*)d_in[7];
  const float* b1 = (const float*)d_in[8];
  const float* W2 = (const float*)d_in[9];
  const float* b2 = (const float*)d_in[10];
  float* out = (float*)d_out;
  char* w = (char*)d_ws;

  // layout (bytes): [0, 4SZ) xT f32  (later: h1 bf16 [0,2SZ) + xsb bf16 [2SZ,4SZ))
  //                 [4SZ, 6SZ) Q bf16 -> xsbT ;  [6SZ, 8SZ) K bf16
  //                 [8SZ, 12SZ) V f32 -> s2T ;   [12SZ, ..) packed weights
  float* xT            = (float*)w;
  unsigned short* Qbf  = (unsigned short*)(w + (size_t)SZ * 4);
  unsigned short* Kbf  = Qbf + SZ;
  float* Vf            = (float*)(w + (size_t)SZ * 8);
  unsigned short* WqkvT = (unsigned short*)(w + (size_t)SZ * 12);
  unsigned short* W1T  = WqkvT + 1536 * 512;
  unsigned short* W2T  = W1T + 512 * 512;
  float* bqkv          = (float*)(W2T + 512 * 512);
  unsigned short* h1   = (unsigned short*)w;
  unsigned short* xsb  = (unsigned short*)(w + (size_t)SZ * 2);
  unsigned short* xsbT = Qbf;
  float* s2T           = Vf;

  k_transpose<<<dim3(16, 8, NB), 256, 0, stream>>>(x, xT);
  k_packw<<<dim3(8, 8), 256, 0, stream>>>(Wq, WqkvT);
  k_packw<<<dim3(8, 8), 256, 0, stream>>>(Wk, WqkvT + 512 * 512);
  k_packw<<<dim3(8, 8), 256, 0, stream>>>(Wv, WqkvT + 1024 * 512);
  k_packw<<<dim3(8, 8), 256, 0, stream>>>(W1, W1T);
  k_packw<<<dim3(8, 8), 256, 0, stream>>>(W2, W2T);
  k_packb<<<dim3(6), 256, 0, stream>>>(bq, bk, bv, bqkv);

  k_mfma<0, true><<<dim3(768), 256, 0, stream>>>(x, WqkvT, bqkv, nullptr, Qbf, Vf, 12);

  k_autocorr<<<dim3(NB * DD), 256, 0, stream>>>(Qbf, Kbf, Vf, xT, xsbT);

  k_castT<<<dim3(16, 8, NB), 256, 0, stream>>>(xsbT, xsb);

  k_mfma<1, false><<<dim3(256), 256, 0, stream>>>(xsb, W1T, b1, nullptr, h1, nullptr, 4);
  k_mfma<2, false><<<dim3(256), 256, 0, stream>>>(h1, W2T, b2, xsbT, nullptr, s2T, 4);

  k_decomp2T<<<dim3(4, 16, NB), 256, 0, stream>>>(s2T, out);
}

// Round 6
// 183.715 us; speedup vs baseline: 3.2812x; 1.1469x over previous
//
#include <hip/hip_runtime.h>
#include <math.h>

#define LL 1024
#define DD 512
#define NB 8
#define KTOP 20
#define SZ (8 * 512 * 1024)  // elems per [B,D,L] plane

typedef __attribute__((ext_vector_type(8))) short bf16x8;
typedef __attribute__((ext_vector_type(4))) float f32x4;
typedef __attribute__((ext_vector_type(4))) int i32x4;

__device__ __forceinline__ unsigned short f2bf(float f) {
  union { float f; unsigned u; } v; v.f = f;
  unsigned r = v.u + 0x7FFFu + ((v.u >> 16) & 1u);
  return (unsigned short)(r >> 16);
}
__device__ __forceinline__ float bf2f(unsigned short u) {
  union { unsigned u; float f; } v; v.u = ((unsigned)u) << 16;
  return v.f;
}

// ================= transpose x [B,L,D] -> xT [B,D,L] (f32) =================
__global__ __launch_bounds__(256) void k_transpose(const float* __restrict__ x,
                                                   float* __restrict__ xT) {
  __shared__ float T[64][65];
  int b = blockIdx.z;
  int t0 = blockIdx.x * 64, c0 = blockIdx.y * 64;
  int tid = threadIdx.x;
  int lane = tid & 63, row4 = tid >> 6;
#pragma unroll
  for (int it = 0; it < 16; ++it) {
    int tl = it * 4 + row4;
    T[lane][tl] = x[((size_t)b * LL + t0 + tl) * DD + c0 + lane];
  }
  __syncthreads();
#pragma unroll
  for (int it = 0; it < 16; ++it) {
    int cl = it * 4 + row4;
    xT[((size_t)b * DD + c0 + cl) * LL + t0 + lane] = T[cl][lane];
  }
}

// ================= pack W [512k][512n] f32 -> dst [n][k] bf16 =================
__global__ __launch_bounds__(256) void k_packw(const float* __restrict__ W,
                                               unsigned short* __restrict__ dst) {
  __shared__ float T[64][65];  // T[n][k]
  int k0 = blockIdx.x * 64, n0 = blockIdx.y * 64;
  int tid = threadIdx.x;
  int lane = tid & 63, r4 = tid >> 6;
#pragma unroll
  for (int it = 0; it < 16; ++it) {
    int kl = it * 4 + r4;
    T[lane][kl] = W[(size_t)(k0 + kl) * DD + n0 + lane];
  }
  __syncthreads();
  int n = tid >> 2, kq = (tid & 3) * 16;
  unsigned short* d = dst + (size_t)(n0 + n) * DD + k0 + kq;
#pragma unroll
  for (int j = 0; j < 16; j += 4) {
    ushort4 u;
    u.x = f2bf(T[n][kq + j]);
    u.y = f2bf(T[n][kq + j + 1]);
    u.z = f2bf(T[n][kq + j + 2]);
    u.w = f2bf(T[n][kq + j + 3]);
    *(ushort4*)&d[j] = u;
  }
}

__global__ __launch_bounds__(256) void k_packb(const float* __restrict__ bq,
                                               const float* __restrict__ bk,
                                               const float* __restrict__ bv,
                                               float* __restrict__ dst) {
  int i = blockIdx.x * 256 + threadIdx.x;  // 0..1535
  const float* s = (i < 512) ? bq : (i < 1024) ? bk : bv;
  dst[i] = s[i & 511];
}

// ================= MFMA GEMM: C[M,N] = A[M,512] @ B^T[N,512], 128x128 tile =====
template <int MODE, bool AF32>
__global__ __launch_bounds__(256) void k_mfma(const void* __restrict__ Aptr,
                                              const unsigned short* __restrict__ Bt,
                                              const float* __restrict__ bias,
                                              const unsigned short* __restrict__ resbT,
                                              unsigned short* __restrict__ outU,
                                              float* __restrict__ outF, int gx) {
  __shared__ char smem[34816];
  unsigned short* As = (unsigned short*)smem;            // [128][64] quad-swizzled
  unsigned short* Bs = (unsigned short*)(smem + 16384);
  float* Cs = (float*)smem;

  int tid = threadIdx.x;
  int lane = tid & 63, wid = tid >> 6;
  int wr = wid & 1, wc = wid >> 1;

  int nwg = gridDim.x;
  int wg = blockIdx.x;
  int swz = (wg & 7) * (nwg >> 3) + (wg >> 3);
  int bix = swz % gx, biy = swz / gx;
  int n0 = bix * 128, m0 = biy * 128;
  int b = m0 >> 10, t0 = m0 & (LL - 1);

  f32x4 acc[4][4];
#pragma unroll
  for (int i = 0; i < 4; ++i)
#pragma unroll
    for (int j = 0; j < 4; ++j) acc[i][j] = (f32x4){0.f, 0.f, 0.f, 0.f};

  int srow = tid >> 3, sq = tid & 7;

  for (int k0 = 0; k0 < 512; k0 += 64) {
#pragma unroll
    for (int p = 0; p < 4; ++p) {
      int r = srow + p * 32;
      int dq = sq ^ (r & 7);
      if (AF32) {
        const float* s = (const float*)Aptr + (size_t)(m0 + r) * 512 + k0 + sq * 8;
        float4 v0 = *(const float4*)s;
        float4 v1 = *(const float4*)(s + 4);
        unsigned short tmp[8];
        tmp[0] = f2bf(v0.x); tmp[1] = f2bf(v0.y); tmp[2] = f2bf(v0.z); tmp[3] = f2bf(v0.w);
        tmp[4] = f2bf(v1.x); tmp[5] = f2bf(v1.y); tmp[6] = f2bf(v1.z); tmp[7] = f2bf(v1.w);
        *(i32x4*)&As[r * 64 + dq * 8] = *(const i32x4*)tmp;
      } else {
        *(i32x4*)&As[r * 64 + dq * 8] =
            *(const i32x4*)((const unsigned short*)Aptr + (size_t)(m0 + r) * 512 + k0 + sq * 8);
      }
      *(i32x4*)&Bs[r * 64 + dq * 8] =
          *(const i32x4*)(Bt + (size_t)(n0 + r) * 512 + k0 + sq * 8);
    }
    __syncthreads();
#pragma unroll
    for (int ks = 0; ks < 2; ++ks) {
      bf16x8 af[4], bf[4];
      int fr = lane & 15, kq = lane >> 4;
#pragma unroll
      for (int mi = 0; mi < 4; ++mi) {
        int r = wr * 64 + mi * 16 + fr;
        af[mi] = *(bf16x8*)&As[r * 64 + ((ks * 4 + kq) ^ (r & 7)) * 8];
      }
#pragma unroll
      for (int ni = 0; ni < 4; ++ni) {
        int r = wc * 64 + ni * 16 + fr;
        bf[ni] = *(bf16x8*)&Bs[r * 64 + ((ks * 4 + kq) ^ (r & 7)) * 8];
      }
#pragma unroll
      for (int mi = 0; mi < 4; ++mi)
#pragma unroll
        for (int ni = 0; ni < 4; ++ni)
          acc[mi][ni] = __builtin_amdgcn_mfma_f32_16x16x32_bf16(af[mi], bf[ni], acc[mi][ni], 0, 0, 0);
    }
    __syncthreads();
  }

  if (MODE == 0 || MODE == 2) {
    const int LDc = 132;
    for (int p = 0; p < 2; ++p) {
      __syncthreads();
      if (MODE == 2) {
        int n = tid >> 2, mq = tid & 3;
        const unsigned short* rrow =
            resbT + ((size_t)(b * 512) + n0 + p * 64 + n) * LL + t0;
#pragma unroll
        for (int i = 0; i < 8; ++i) {
          int m = mq * 4 + i * 16;
          ushort4 u = *(const ushort4*)&rrow[m];
          float4 v;
          v.x = bf2f(u.x); v.y = bf2f(u.y); v.z = bf2f(u.z); v.w = bf2f(u.w);
          *(float4*)&Cs[n * LDc + m] = v;
        }
        __syncthreads();
      }
      if (wc == p) {
#pragma unroll
        for (int mi = 0; mi < 4; ++mi)
#pragma unroll
          for (int ni = 0; ni < 4; ++ni) {
            int nl = ni * 16 + (lane & 15);
            int ml = wr * 64 + mi * 16 + (lane >> 4) * 4;
            if (MODE == 2) {
              f32x4 cur = *(f32x4*)&Cs[nl * LDc + ml];
              cur += acc[mi][ni];
              *(f32x4*)&Cs[nl * LDc + ml] = cur;
            } else {
              *(f32x4*)&Cs[nl * LDc + ml] = acc[mi][ni];
            }
          }
      }
      __syncthreads();
      {
        int n = tid >> 2, mq = tid & 3;
        int ng = n0 + p * 64 + n;
        float bv = bias[ng];
        if (MODE == 0 && ng < 1024) {
          int sel = ng >> 9;
          unsigned short* drow =
              outU + ((size_t)sel * NB * 512 + b * 512 + (ng & 511)) * LL + t0;
#pragma unroll
          for (int i = 0; i < 8; ++i) {
            int m = mq * 4 + i * 16;
            float4 v = *(float4*)&Cs[n * LDc + m];
            ushort4 u;
            u.x = f2bf(v.x + bv); u.y = f2bf(v.y + bv);
            u.z = f2bf(v.z + bv); u.w = f2bf(v.w + bv);
            *(ushort4*)&drow[m] = u;
          }
        } else {
          int cch = (MODE == 0) ? (ng - 1024) : ng;
          float* drow = outF + ((size_t)b * 512 + cch) * LL + t0;
#pragma unroll
          for (int i = 0; i < 8; ++i) {
            int m = mq * 4 + i * 16;
            float4 v = *(float4*)&Cs[n * LDc + m];
            v.x += bv; v.y += bv; v.z += bv; v.w += bv;
            *(float4*)&drow[m] = v;
          }
        }
      }
    }
  } else {  // MODE 1
    const int LDh = 68;
    for (int p = 0; p < 2; ++p) {
      __syncthreads();
      if (wc == p) {
#pragma unroll
        for (int mi = 0; mi < 4; ++mi)
#pragma unroll
          for (int ni = 0; ni < 4; ++ni) {
            int nl = ni * 16 + (lane & 15);
            int ml = wr * 64 + mi * 16 + (lane >> 4) * 4;
#pragma unroll
            for (int r = 0; r < 4; ++r) Cs[(ml + r) * LDh + nl] = acc[mi][ni][r];
          }
      }
      __syncthreads();
      {
        int m = tid >> 1, nh = tid & 1;
        unsigned short* drow =
            outU + (size_t)(m0 + m) * 512 + n0 + p * 64 + nh * 32;
#pragma unroll
        for (int c = 0; c < 8; ++c) {
          float4 v = *(float4*)&Cs[m * LDh + nh * 32 + c * 4];
          float4 bb = *(const float4*)&bias[n0 + p * 64 + nh * 32 + c * 4];
          v.x = fmaxf(v.x + bb.x, 0.f);
          v.y = fmaxf(v.y + bb.y, 0.f);
          v.z = fmaxf(v.z + bb.z, 0.f);
          v.w = fmaxf(v.w + bb.w, 0.f);
          ushort4 u;
          u.x = f2bf(v.x); u.y = f2bf(v.y); u.z = f2bf(v.z); u.w = f2bf(v.w);
          *(ushort4*)&drow[c * 4] = u;
        }
      }
    }
  }
}

// ================= autocorr (MFMA) + topk + softmax + aggregate + decomp1 =====
// One WG (4 waves) per (b,channel).  tau = 256g + 16m + n.
//   C_g[m,n] = sum_k Q[(k+16m+256g)%L] * K[(k-n)%L]
// A-frag: aligned b128 from duplicated Q.  B-frag: n = 2a+b -> row b of the
// 2-row shifted table Ksh2[b][p]=K[p-b], read at 4B-aligned offset k-2a via
// 4x ds_read_b32.  Row 1 is built IN REGISTERS during stage (funnel shift +
// shfl seam).  LDS 20.3 KB -> 7 WG/CU.  4 barriers total.
__global__ __launch_bounds__(256) void k_autocorr(const unsigned short* __restrict__ Qbf,
                                                  const unsigned short* __restrict__ Kbf,
                                                  const float* __restrict__ Vf,
                                                  const float* __restrict__ xT,
                                                  unsigned short* __restrict__ xsbT) {
  __shared__ char sm[20768];
  unsigned short* Qs2  = (unsigned short*)sm;            // [2048] bf16 (Q dup)
  unsigned short* Ksh2 = (unsigned short*)(sm + 4096);   // [2][1056] bf16
  float* Vs2 = (float*)(sm + 8320);                      // [2048] f32 (V + sat tail)
  float* Cp  = (float*)(sm + 16512);                     // [1024] f32
  float* Csp = (float*)sm;                               // [1056] aliases Qs2/Ksh2
  float* wvs = (float*)(sm + 20608);                     // [20]
  int*   wis = (int*)(sm + 20688);                       // [20]

  int tid = threadIdx.x;
  int lane = tid & 63, wave = tid >> 6;
  size_t base = (size_t)blockIdx.x * LL;

  // ---- stage: Q dup, V + saturating tail, Ksh2 rows 0 & 1 ----
  {
    ushort4 q = *(const ushort4*)(Qbf + base + tid * 4);
    *(ushort4*)&Qs2[tid * 4] = q;
    *(ushort4*)&Qs2[1024 + tid * 4] = q;
    float4 v = *(const float4*)(Vf + base + tid * 4);
    *(float4*)&Vs2[tid * 4] = v;
    float vlast = Vf[base + 1023];
    float4 vl4 = make_float4(vlast, vlast, vlast, vlast);
    *(float4*)&Vs2[1024 + tid * 4] = vl4;

    ushort4 kv = *(const ushort4*)(Kbf + base + tid * 4);
    *(ushort4*)&Ksh2[16 + tid * 4] = kv;  // row0 body: Ksh2[0][16+4t] = K[4t]
    unsigned w0 = (unsigned)kv.x | ((unsigned)kv.y << 16);
    unsigned w1 = (unsigned)kv.z | ((unsigned)kv.w << 16);
    unsigned wn = __shfl_down(w0, 1);
    if (lane == 63) {
      int e = (tid * 4 + 4) & (LL - 1);
      wn = *(const unsigned*)(Kbf + base + e);
    }
    unsigned r1a = (w0 >> 16) | (w1 << 16);  // (K[4t+1],K[4t+2]) -> row1 p=4t+2
    unsigned r1b = (w1 >> 16) | (wn << 16);  // (K[4t+3],K[4t+4]) -> row1 p=4t+4
    *(unsigned*)&Ksh2[1056 + 16 + tid * 4 + 2] = r1a;
    *(unsigned*)&Ksh2[1056 + 16 + tid * 4 + 4] = r1b;
    if (tid < 8) {
      // row0 prefix p in [-16,0): K[(p)&1023], pairs aligned even in K
      unsigned v2 = *(const unsigned*)(Kbf + base + 1008 + 2 * tid);
      *(unsigned*)&Ksh2[2 * tid] = v2;
    } else if (tid < 17) {
      // row1 prefix p in [-16,2): values (K[2j-17], K[2j-16]) mod 1024
      int j = tid - 8;  // 0..8
      unsigned short a = Kbf[base + ((2 * j - 17) & (LL - 1))];
      unsigned short b = Kbf[base + ((2 * j - 16) & (LL - 1))];
      *(unsigned*)&Ksh2[1056 + 2 * j] = (unsigned)a | ((unsigned)b << 16);
    }
  }
  __syncthreads();

  // ---- correlation via MFMA: 32 K-steps, one g per wave ----
  f32x4 acc = (f32x4){0.f, 0.f, 0.f, 0.f};
  int fr = lane & 15, kq = lane >> 4;  // kq in [0,4)
  int g = wave;
  const unsigned short* Arow = Qs2 + 256 * g + 16 * fr + kq * 8;
  const unsigned short* Brow = Ksh2 + (fr & 1) * 1056 + 16 + kq * 8 - 2 * (fr >> 1);
#pragma unroll
  for (int ks = 0; ks < 32; ++ks) {
    bf16x8 av = *(const bf16x8*)(Arow + ks * 32);
    const unsigned short* bp = Brow + ks * 32;
    union { i32x4 i; bf16x8 h; } u;
    u.i[0] = *(const int*)(bp);
    u.i[1] = *(const int*)(bp + 2);
    u.i[2] = *(const int*)(bp + 4);
    u.i[3] = *(const int*)(bp + 6);
    acc = __builtin_amdgcn_mfma_f32_16x16x32_bf16(av, u.h, acc, 0, 0, 0);
  }
#pragma unroll
  for (int r = 0; r < 4; ++r) Cp[256 * g + 16 * (kq * 4 + r) + fr] = acc[r];
  __syncthreads();

  // ---- top-20 on wave 'sel'; other waves write Csp pads ----
  int sel = blockIdx.x & 3;
  if (wave == sel) {
    float c0[16];
#pragma unroll
    for (int qd = 0; qd < 4; ++qd)
      *(float4*)&c0[qd * 4] = *(const float4*)&Cp[lane * 16 + qd * 4];
    float lbest = c0[0];
    int lidx = 0;
#pragma unroll
    for (int m = 1; m < 16; ++m)
      if (c0[m] > lbest) { lbest = c0[m]; lidx = m; }

    float wv[KTOP];
    int wiR[KTOP];
#pragma unroll
    for (int s = 0; s < KTOP; ++s) {
      float best = lbest;
      int bidx = lane * 16 + lidx;
#pragma unroll
      for (int off = 32; off; off >>= 1) {
        float v2 = __shfl_xor(best, off);
        int i2 = __shfl_xor(bidx, off);
        if (v2 > best || (v2 == best && i2 < bidx)) { best = v2; bidx = i2; }
      }
      wv[s] = best;
      wiR[s] = bidx;
      int kill = ((bidx >> 4) == lane) ? (bidx & 15) : -1;
#pragma unroll
      for (int m = 0; m < 16; ++m)
        if (m == kill) c0[m] = -3.0e38f;
      lbest = c0[0];
      lidx = 0;
#pragma unroll
      for (int m = 1; m < 16; ++m)
        if (c0[m] > lbest) { lbest = c0[m]; lidx = m; }
    }
    float mx = wv[0];
#pragma unroll
    for (int m = 1; m < KTOP; ++m) mx = fmaxf(mx, wv[m]);
    float ssum = 0.f;
#pragma unroll
    for (int m = 0; m < KTOP; ++m) {
      wv[m] = __expf(wv[m] - mx);
      ssum += wv[m];
    }
    float inv = 1.f / ssum;
    if (lane == 0) {
#pragma unroll
      for (int m = 0; m < KTOP; ++m) {
        wvs[m] = wv[m] * inv;
        wis[m] = wiR[m];
      }
    }
  } else {
    int ft = (wave < sel ? wave : wave - 1) * 64 + lane;  // 0..191
    if (ft < 16) Csp[ft] = 0.f;                 // front pad
    else if (ft < 32) Csp[1040 + ft - 16] = 0.f;  // back pad
  }
  __syncthreads();

  // ---- aggregate (saturating shift) + residual -> padded series ----
  {
    int t0 = tid * 4;
    float4 xr = *(const float4*)(xT + base + t0);
    float r0 = xr.x, r1 = xr.y, r2 = xr.z, r3 = xr.w;
#pragma unroll
    for (int k = 0; k < KTOP; ++k) {
      float w = wvs[k];
      int wi = wis[k];
      r0 += w * Vs2[wi + t0];
      r1 += w * Vs2[wi + t0 + 1];
      r2 += w * Vs2[wi + t0 + 2];
      r3 += w * Vs2[wi + t0 + 3];
    }
    float4 rv;
    rv.x = r0; rv.y = r1; rv.z = r2; rv.w = r3;
    *(float4*)&Csp[16 + t0] = rv;
  }
  __syncthreads();

  // ---- series_decomp #1 -> bf16 chan-major ----
  {
    int t0 = tid * 4;
    float buf[28];
#pragma unroll
    for (int qd = 0; qd < 7; ++qd)
      *(float4*)&buf[qd * 4] = *(const float4*)&Csp[t0 + 4 + qd * 4];
    float s = 0.f;
#pragma unroll
    for (int m = 0; m < 25; ++m) s += buf[m];
    ushort4 o;
    o.x = f2bf(buf[12] - s * (1.0f / 25.0f));
    s += buf[25] - buf[0];
    o.y = f2bf(buf[13] - s * (1.0f / 25.0f));
    s += buf[26] - buf[1];
    o.z = f2bf(buf[14] - s * (1.0f / 25.0f));
    s += buf[27] - buf[2];
    o.w = f2bf(buf[15] - s * (1.0f / 25.0f));
    *(ushort4*)&xsbT[base + t0] = o;
  }
}

// ================= xsbT [c][t] bf16 -> xsb [t][c] bf16 =================
__global__ __launch_bounds__(256) void k_castT(const unsigned short* __restrict__ src,
                                               unsigned short* __restrict__ dst) {
  __shared__ unsigned short T[64][68];
  int b = blockIdx.z;
  int t0 = blockIdx.x * 64, c0 = blockIdx.y * 64;
  int tid = threadIdx.x;
  int lane = tid & 63, r4 = tid >> 6;
#pragma unroll
  for (int it = 0; it < 16; ++it) {
    int cl = it * 4 + r4;
    T[lane][cl] = src[((size_t)b * 512 + c0 + cl) * LL + t0 + lane];
  }
  __syncthreads();
  int tl = tid >> 2, cq = (tid & 3) * 16;
  unsigned short* d = dst + ((size_t)b * LL + t0 + tl) * 512 + c0 + cq;
#pragma unroll
  for (int j = 0; j < 16; j += 4) {
    ushort4 u;
    u.x = T[tl][cq + j]; u.y = T[tl][cq + j + 1];
    u.z = T[tl][cq + j + 2]; u.w = T[tl][cq + j + 3];
    *(ushort4*)&d[j] = u;
  }
}

// ================= final decomp: s2T [c][t] f32 -> out [t][c] f32 =================
#define DCH 32
__global__ __launch_bounds__(256) void k_decomp2T(const float* __restrict__ s2T,
                                                  float* __restrict__ out) {
  __shared__ float T[DCH][289];
  int b = blockIdx.z, c0 = blockIdx.y * DCH, t0 = blockIdx.x * 256;
  int tid = threadIdx.x;
  {
    int row = tid >> 3, j0 = tid & 7;
    const float* src = s2T + ((size_t)b * 512 + c0 + row) * LL;
#pragma unroll
    for (int i = 0; i < 9; ++i) {
      int col = (j0 + i * 8) * 4;
      int t = t0 - 16 + col;
      float4 v = make_float4(0.f, 0.f, 0.f, 0.f);
      if (t >= 0 && t < LL) v = *(const float4*)&src[t];
      *(float4*)&T[row][col] = v;
    }
  }
  __syncthreads();
  int c = tid & 31, tg = tid >> 5;
  float sum = 0.f;
  int basec = tg * 32 + 4;
#pragma unroll
  for (int j = 0; j < 25; ++j) sum += T[c][basec + j];
  float* orow = out + ((size_t)b * LL + t0 + tg * 32) * 512 + c0 + c;
#pragma unroll 1
  for (int s = 0; s < 32; ++s) {
    float center = T[c][tg * 32 + 16 + s];
    orow[(size_t)s * 512] = center - sum * (1.f / 25.f);
    sum += T[c][basec + 25 + s] - T[c][basec + s];
  }
}

// ================= launch =================
extern "C" void kernel_launch(void* const* d_in, const int* in_sizes, int n_in,
                              void* d_out, int out_size, void* d_ws, size_t ws_size,
                              hipStream_t stream) {
  const float* x  = (const float*)d_in[0];
  const float* Wq = (const float*)d_in[1];
  const float* bq = (const float*)d_in[2];
  const float* Wk = (const float*)d_in[3];
  const float* bk = (const float*)d_in[4];
  const float* Wv = (const float*)d_in[5];
  const float* bv = (const float*)d_in[6];
  const float* W1 = (const float*)d_in[7];
  const float* b1 = (const float*)d_in[8];
  const float* W2 = (const float*)d_in[9];
  const float* b2 = (const float*)d_in[10];
  float* out = (float*)d_out;
  char* w = (char*)d_ws;

  float* xT            = (float*)w;
  unsigned short* Qbf  = (unsigned short*)(w + (size_t)SZ * 4);
  unsigned short* Kbf  = Qbf + SZ;
  float* Vf            = (float*)(w + (size_t)SZ * 8);
  unsigned short* WqkvT = (unsigned short*)(w + (size_t)SZ * 12);
  unsigned short* W1T  = WqkvT + 1536 * 512;
  unsigned short* W2T  = W1T + 512 * 512;
  float* bqkv          = (float*)(W2T + 512 * 512);
  unsigned short* h1   = (unsigned short*)w;
  unsigned short* xsb  = (unsigned short*)(w + (size_t)SZ * 2);
  unsigned short* xsbT = Qbf;
  float* s2T           = Vf;

  k_transpose<<<dim3(16, 8, NB), 256, 0, stream>>>(x, xT);
  k_packw<<<dim3(8, 8), 256, 0, stream>>>(Wq, WqkvT);
  k_packw<<<dim3(8, 8), 256, 0, stream>>>(Wk, WqkvT + 512 * 512);
  k_packw<<<dim3(8, 8), 256, 0, stream>>>(Wv, WqkvT + 1024 * 512);
  k_packw<<<dim3(8, 8), 256, 0, stream>>>(W1, W1T);
  k_packw<<<dim3(8, 8), 256, 0, stream>>>(W2, W2T);
  k_packb<<<dim3(6), 256, 0, stream>>>(bq, bk, bv, bqkv);

  k_mfma<0, true><<<dim3(768), 256, 0, stream>>>(x, WqkvT, bqkv, nullptr, Qbf, Vf, 12);

  k_autocorr<<<dim3(NB * DD), 256, 0, stream>>>(Qbf, Kbf, Vf, xT, xsbT);

  k_castT<<<dim3(16, 8, NB), 256, 0, stream>>>(xsbT, xsb);

  k_mfma<1, false><<<dim3(256), 256, 0, stream>>>(xsb, W1T, b1, nullptr, h1, nullptr, 4);
  k_mfma<2, false><<<dim3(256), 256, 0, stream>>>(h1, W2T, b2, xsbT, nullptr, s2T, 4);

  k_decomp2T<<<dim3(4, 16, NB), 256, 0, stream>>>(s2T, out);
}

// Round 7
// 158.247 us; speedup vs baseline: 3.8093x; 1.1609x over previous
//
#include <hip/hip_runtime.h>
#include <math.h>

#define LL 1024
#define DD 512
#define NB 8
#define KTOP 20
#define SZ (8 * 512 * 1024)  // elems per [B,D,L] plane

typedef __attribute__((ext_vector_type(8))) short bf16x8;
typedef __attribute__((ext_vector_type(4))) float f32x4;
typedef __attribute__((ext_vector_type(4))) int i32x4;

__device__ __forceinline__ unsigned short f2bf(float f) {
  union { float f; unsigned u; } v; v.f = f;
  unsigned r = v.u + 0x7FFFu + ((v.u >> 16) & 1u);
  return (unsigned short)(r >> 16);
}
__device__ __forceinline__ float bf2f(unsigned short u) {
  union { unsigned u; float f; } v; v.u = ((unsigned)u) << 16;
  return v.f;
}

// ======== transpose x [B,L,D] -> xT [B,D,L] f32  AND  xb [B,L,D] bf16 ========
__global__ __launch_bounds__(256) void k_transpose(const float* __restrict__ x,
                                                   float* __restrict__ xT,
                                                   unsigned short* __restrict__ xb) {
  __shared__ float T[64][65];  // T[c_local][t_local]
  int b = blockIdx.z;
  int t0 = blockIdx.x * 64, c0 = blockIdx.y * 64;
  int tid = threadIdx.x;
  int lane = tid & 63, row4 = tid >> 6;
#pragma unroll
  for (int it = 0; it < 16; ++it) {
    int tl = it * 4 + row4;
    T[lane][tl] = x[((size_t)b * LL + t0 + tl) * DD + c0 + lane];
  }
  __syncthreads();
#pragma unroll
  for (int it = 0; it < 16; ++it) {
    int cl = it * 4 + row4;
    xT[((size_t)b * DD + c0 + cl) * LL + t0 + lane] = T[cl][lane];
  }
  // token-major bf16 copy (for QKV GEMM A-side)
  int tl2 = tid >> 2, cq = (tid & 3) * 16;
  unsigned short* dxb = xb + ((size_t)b * LL + t0 + tl2) * DD + c0 + cq;
#pragma unroll
  for (int j = 0; j < 16; j += 4) {
    ushort4 u;
    u.x = f2bf(T[cq + j][tl2]);
    u.y = f2bf(T[cq + j + 1][tl2]);
    u.z = f2bf(T[cq + j + 2][tl2]);
    u.w = f2bf(T[cq + j + 3][tl2]);
    *(ushort4*)&dxb[j] = u;
  }
}

// ======== pack all weights [512k][512n] f32 -> [n][k] bf16 (+ qkv bias) ========
__global__ __launch_bounds__(256) void k_packall(const float* __restrict__ Wq,
                                                 const float* __restrict__ Wk,
                                                 const float* __restrict__ Wv,
                                                 const float* __restrict__ W1,
                                                 const float* __restrict__ W2,
                                                 const float* __restrict__ bq,
                                                 const float* __restrict__ bk,
                                                 const float* __restrict__ bv,
                                                 unsigned short* __restrict__ WqkvT,
                                                 unsigned short* __restrict__ W1T,
                                                 unsigned short* __restrict__ W2T,
                                                 float* __restrict__ bqkv) {
  __shared__ float T[64][65];  // T[n][k]
  int z = blockIdx.z;
  const float* W = (z == 0) ? Wq : (z == 1) ? Wk : (z == 2) ? Wv : (z == 3) ? W1 : W2;
  unsigned short* dst = (z == 0) ? WqkvT
                      : (z == 1) ? (WqkvT + 512 * 512)
                      : (z == 2) ? (WqkvT + 1024 * 512)
                      : (z == 3) ? W1T : W2T;
  int k0 = blockIdx.x * 64, n0 = blockIdx.y * 64;
  int tid = threadIdx.x;
  int lane = tid & 63, r4 = tid >> 6;
#pragma unroll
  for (int it = 0; it < 16; ++it) {
    int kl = it * 4 + r4;
    T[lane][kl] = W[(size_t)(k0 + kl) * DD + n0 + lane];
  }
  __syncthreads();
  int n = tid >> 2, kq = (tid & 3) * 16;
  unsigned short* d = dst + (size_t)(n0 + n) * DD + k0 + kq;
#pragma unroll
  for (int j = 0; j < 16; j += 4) {
    ushort4 u;
    u.x = f2bf(T[n][kq + j]);
    u.y = f2bf(T[n][kq + j + 1]);
    u.z = f2bf(T[n][kq + j + 2]);
    u.w = f2bf(T[n][kq + j + 3]);
    *(ushort4*)&d[j] = u;
  }
  if (z == 4 && blockIdx.x == 0 && blockIdx.y == 0) {
    for (int i = tid; i < 1536; i += 256) {
      const float* s = (i < 512) ? bq : (i < 1024) ? bk : bv;
      bqkv[i] = s[i & 511];
    }
  }
}

// ======== MFMA GEMM: C[M,N] = A[M,512] @ B^T[N,512], 128x128 tile ========
// MODE 0: bias; out bf16 chan-major (n<1024: Q/K) or f32 chan-major (n>=1024: V)
// MODE 1: bias+relu; out bf16 token-major (h1)
// MODE 2: bias+residual(resbT bf16 chan-major); out f32 chan-major (s2T)
template <int MODE>
__global__ __launch_bounds__(256) void k_mfma(const unsigned short* __restrict__ Aptr,
                                              const unsigned short* __restrict__ Bt,
                                              const float* __restrict__ bias,
                                              const unsigned short* __restrict__ resbT,
                                              unsigned short* __restrict__ outU,
                                              float* __restrict__ outF, int gx) {
  __shared__ char smem[34816];
  unsigned short* As = (unsigned short*)smem;            // [128][64] quad-swizzled
  unsigned short* Bs = (unsigned short*)(smem + 16384);
  float* Cs = (float*)smem;

  int tid = threadIdx.x;
  int lane = tid & 63, wid = tid >> 6;
  int wr = wid & 1, wc = wid >> 1;

  int nwg = gridDim.x;
  int wg = blockIdx.x;
  int swz = (wg & 7) * (nwg >> 3) + (wg >> 3);
  int bix = swz % gx, biy = swz / gx;
  int n0 = bix * 128, m0 = biy * 128;
  int b = m0 >> 10, t0 = m0 & (LL - 1);

  f32x4 acc[4][4];
#pragma unroll
  for (int i = 0; i < 4; ++i)
#pragma unroll
    for (int j = 0; j < 4; ++j) acc[i][j] = (f32x4){0.f, 0.f, 0.f, 0.f};

  int srow = tid >> 3, sq = tid & 7;

  for (int k0 = 0; k0 < 512; k0 += 64) {
#pragma unroll
    for (int p = 0; p < 4; ++p) {
      int r = srow + p * 32;
      int dq = sq ^ (r & 7);
      *(i32x4*)&As[r * 64 + dq * 8] =
          *(const i32x4*)(Aptr + (size_t)(m0 + r) * 512 + k0 + sq * 8);
      *(i32x4*)&Bs[r * 64 + dq * 8] =
          *(const i32x4*)(Bt + (size_t)(n0 + r) * 512 + k0 + sq * 8);
    }
    __syncthreads();
#pragma unroll
    for (int ks = 0; ks < 2; ++ks) {
      bf16x8 af[4], bf[4];
      int fr = lane & 15, kq = lane >> 4;
#pragma unroll
      for (int mi = 0; mi < 4; ++mi) {
        int r = wr * 64 + mi * 16 + fr;
        af[mi] = *(bf16x8*)&As[r * 64 + ((ks * 4 + kq) ^ (r & 7)) * 8];
      }
#pragma unroll
      for (int ni = 0; ni < 4; ++ni) {
        int r = wc * 64 + ni * 16 + fr;
        bf[ni] = *(bf16x8*)&Bs[r * 64 + ((ks * 4 + kq) ^ (r & 7)) * 8];
      }
#pragma unroll
      for (int mi = 0; mi < 4; ++mi)
#pragma unroll
        for (int ni = 0; ni < 4; ++ni)
          acc[mi][ni] = __builtin_amdgcn_mfma_f32_16x16x32_bf16(af[mi], bf[ni], acc[mi][ni], 0, 0, 0);
    }
    __syncthreads();
  }

  if (MODE == 0 || MODE == 2) {
    const int LDc = 132;
    for (int p = 0; p < 2; ++p) {
      __syncthreads();
      if (MODE == 2) {
        int n = tid >> 2, mq = tid & 3;
        const unsigned short* rrow =
            resbT + ((size_t)(b * 512) + n0 + p * 64 + n) * LL + t0;
#pragma unroll
        for (int i = 0; i < 8; ++i) {
          int m = mq * 4 + i * 16;
          ushort4 u = *(const ushort4*)&rrow[m];
          float4 v;
          v.x = bf2f(u.x); v.y = bf2f(u.y); v.z = bf2f(u.z); v.w = bf2f(u.w);
          *(float4*)&Cs[n * LDc + m] = v;
        }
        __syncthreads();
      }
      if (wc == p) {
#pragma unroll
        for (int mi = 0; mi < 4; ++mi)
#pragma unroll
          for (int ni = 0; ni < 4; ++ni) {
            int nl = ni * 16 + (lane & 15);
            int ml = wr * 64 + mi * 16 + (lane >> 4) * 4;
            if (MODE == 2) {
              f32x4 cur = *(f32x4*)&Cs[nl * LDc + ml];
              cur += acc[mi][ni];
              *(f32x4*)&Cs[nl * LDc + ml] = cur;
            } else {
              *(f32x4*)&Cs[nl * LDc + ml] = acc[mi][ni];
            }
          }
      }
      __syncthreads();
      {
        int n = tid >> 2, mq = tid & 3;
        int ng = n0 + p * 64 + n;
        float bv = bias[ng];
        if (MODE == 0 && ng < 1024) {
          int sel = ng >> 9;
          unsigned short* drow =
              outU + ((size_t)sel * NB * 512 + b * 512 + (ng & 511)) * LL + t0;
#pragma unroll
          for (int i = 0; i < 8; ++i) {
            int m = mq * 4 + i * 16;
            float4 v = *(float4*)&Cs[n * LDc + m];
            ushort4 u;
            u.x = f2bf(v.x + bv); u.y = f2bf(v.y + bv);
            u.z = f2bf(v.z + bv); u.w = f2bf(v.w + bv);
            *(ushort4*)&drow[m] = u;
          }
        } else {
          int cch = (MODE == 0) ? (ng - 1024) : ng;
          float* drow = outF + ((size_t)b * 512 + cch) * LL + t0;
#pragma unroll
          for (int i = 0; i < 8; ++i) {
            int m = mq * 4 + i * 16;
            float4 v = *(float4*)&Cs[n * LDc + m];
            v.x += bv; v.y += bv; v.z += bv; v.w += bv;
            *(float4*)&drow[m] = v;
          }
        }
      }
    }
  } else {  // MODE 1
    const int LDh = 68;
    for (int p = 0; p < 2; ++p) {
      __syncthreads();
      if (wc == p) {
#pragma unroll
        for (int mi = 0; mi < 4; ++mi)
#pragma unroll
          for (int ni = 0; ni < 4; ++ni) {
            int nl = ni * 16 + (lane & 15);
            int ml = wr * 64 + mi * 16 + (lane >> 4) * 4;
#pragma unroll
            for (int r = 0; r < 4; ++r) Cs[(ml + r) * LDh + nl] = acc[mi][ni][r];
          }
      }
      __syncthreads();
      {
        int m = tid >> 1, nh = tid & 1;
        unsigned short* drow =
            outU + (size_t)(m0 + m) * 512 + n0 + p * 64 + nh * 32;
#pragma unroll
        for (int c = 0; c < 8; ++c) {
          float4 v = *(float4*)&Cs[m * LDh + nh * 32 + c * 4];
          float4 bb = *(const float4*)&bias[n0 + p * 64 + nh * 32 + c * 4];
          v.x = fmaxf(v.x + bb.x, 0.f);
          v.y = fmaxf(v.y + bb.y, 0.f);
          v.z = fmaxf(v.z + bb.z, 0.f);
          v.w = fmaxf(v.w + bb.w, 0.f);
          ushort4 u;
          u.x = f2bf(v.x); u.y = f2bf(v.y); u.z = f2bf(v.z); u.w = f2bf(v.w);
          *(ushort4*)&drow[c * 4] = u;
        }
      }
    }
  }
}

// ======== autocorr (MFMA) + topk + softmax + aggregate + decomp1 ========
// One WG (4 waves) per (b,channel). tau = 256g + 64kq + 16r + fr.
// A-frag: swizzled b128 from duplicated Q. B-frag: lane fr=4f'+s reads row s of
// Ksh4 (Ksh4[s][p]=K[p-s], built in-registers at stage) at 8B-aligned offset
// k-4f' -> 2x ds_read_b64. Cp tau-swizzled; topk lane owns taus {64j+lane}.
// Aggregate: interleaved t (lane-stride-1, conflict-free) + index clamp.
__global__ __launch_bounds__(256) void k_autocorr(const unsigned short* __restrict__ Qbf,
                                                  const unsigned short* __restrict__ Kbf,
                                                  const float* __restrict__ Vf,
                                                  const float* __restrict__ xT,
                                                  unsigned short* __restrict__ xsbT) {
  __shared__ char sm[20768];
  unsigned* QsW  = (unsigned*)sm;             // [1024] dwords: Q dup, XOR-swizzled
  unsigned* KshW = (unsigned*)(sm + 4096);    // [2080] dwords: 4 rows x 520
  float* Vs  = (float*)(sm + 12416);          // [1024]
  float* Cp  = (float*)(sm + 16512);          // [1024], tau-swizzled
  float* wvs = (float*)(sm + 20608);          // [20]
  int*   wis = (int*)(sm + 20688);            // [20]
  float* Csp = (float*)sm;                    // [1056] padded series (alias Q/Ksh)

  int tid = threadIdx.x;
  int lane = tid & 63, wave = tid >> 6;
  size_t base = (size_t)blockIdx.x * LL;

  // ---- stage ----
  {
    ushort4 q = *(const ushort4*)(Qbf + base + tid * 4);
    unsigned q0 = (unsigned)q.x | ((unsigned)q.y << 16);
    unsigned q1 = (unsigned)q.z | ((unsigned)q.w << 16);
    int Wa = 2 * tid;
    int Pa = Wa ^ (((Wa >> 5) & 3) << 2);
    uint2 qv; qv.x = q0; qv.y = q1;
    *(uint2*)&QsW[Pa] = qv;
    int Wb = 512 + 2 * tid;
    int Pb = Wb ^ (((Wb >> 5) & 3) << 2);
    *(uint2*)&QsW[Pb] = qv;

    *(float4*)&Vs[tid * 4] = *(const float4*)(Vf + base + tid * 4);

    ushort4 kv = *(const ushort4*)(Kbf + base + tid * 4);
    unsigned w0 = (unsigned)kv.x | ((unsigned)kv.y << 16);
    unsigned w1 = (unsigned)kv.z | ((unsigned)kv.w << 16);
    unsigned wq = __shfl_up(w0, 1);
    unsigned wp = __shfl_up(w1, 1);
    if (lane == 0) {
      wq = *(const unsigned*)(Kbf + base + ((tid * 4 - 4) & (LL - 1)));
      wp = *(const unsigned*)(Kbf + base + ((tid * 4 - 2) & (LL - 1)));
    }
    int d = 8 + 2 * tid;
    uint2 u0; u0.x = w0;                              u0.y = w1;
    uint2 u1; u1.x = (wp >> 16) | (w0 << 16);         u1.y = (w0 >> 16) | (w1 << 16);
    uint2 u2; u2.x = wp;                              u2.y = w0;
    uint2 u3; u3.x = (wq >> 16) | (wp << 16);         u3.y = (wp >> 16) | (w0 << 16);
    *(uint2*)&KshW[d]            = u0;
    *(uint2*)&KshW[520 + d]      = u1;
    *(uint2*)&KshW[1040 + d]     = u2;
    *(uint2*)&KshW[1560 + d]     = u3;
    if (tid >= 224) {  // wrap prefix p in [-16,0): 4 rows x 8 dwords
      int q2 = tid - 224;
      int s = q2 >> 3, dd = q2 & 7;
      int p = 2 * dd - 16;
      unsigned short a = Kbf[base + ((p - s) & (LL - 1))];
      unsigned short b2 = Kbf[base + ((p + 1 - s) & (LL - 1))];
      KshW[s * 520 + dd] = (unsigned)a | ((unsigned)b2 << 16);
    }
  }
  __syncthreads();

  // ---- correlation via MFMA: 32 K-steps, one g per wave ----
  f32x4 acc = (f32x4){0.f, 0.f, 0.f, 0.f};
  int fr = lane & 15, kq = lane >> 4;
  int g = wave;
  int srow = fr & 3, fp = fr >> 2;
  int aW0 = 128 * g + 8 * fr + 4 * kq;
  int bD0 = srow * 520 + 8 + 4 * kq - 2 * fp;
#pragma unroll
  for (int ks = 0; ks < 32; ++ks) {
    int W = aW0 + 16 * ks;
    int Pw = W ^ (((W >> 5) & 3) << 2);
    bf16x8 av = *(const bf16x8*)&QsW[Pw];
    int bD = bD0 + 16 * ks;
    uint2 b01 = *(const uint2*)&KshW[bD];
    uint2 b23 = *(const uint2*)&KshW[bD + 2];
    union { unsigned u[4]; bf16x8 h; } ub;
    ub.u[0] = b01.x; ub.u[1] = b01.y; ub.u[2] = b23.x; ub.u[3] = b23.y;
    acc = __builtin_amdgcn_mfma_f32_16x16x32_bf16(av, ub.h, acc, 0, 0, 0);
  }
#pragma unroll
  for (int r = 0; r < 4; ++r) {
    int tau = 256 * g + 64 * kq + 16 * r + fr;
    Cp[tau ^ (((tau >> 6) & 3) << 4)] = acc[r];
  }
  __syncthreads();

  // ---- top-20 on wave 'sel'; other waves write Csp pads ----
  int sel = blockIdx.x & 3;
  if (wave == sel) {
    float c0[16];
#pragma unroll
    for (int j = 0; j < 16; ++j) {
      int tau = 64 * j + lane;
      c0[j] = Cp[tau ^ (((tau >> 6) & 3) << 4)];
    }
    float lbest = c0[0];
    int lidx = 0;
#pragma unroll
    for (int m = 1; m < 16; ++m)
      if (c0[m] > lbest) { lbest = c0[m]; lidx = m; }

    float wv[KTOP];
    int wiR[KTOP];
#pragma unroll
    for (int s = 0; s < KTOP; ++s) {
      float best = lbest;
      int bidx = 64 * lidx + lane;
#pragma unroll
      for (int off = 32; off; off >>= 1) {
        float v2 = __shfl_xor(best, off);
        int i2 = __shfl_xor(bidx, off);
        if (v2 > best || (v2 == best && i2 < bidx)) { best = v2; bidx = i2; }
      }
      wv[s] = best;
      wiR[s] = bidx;
      int kill = ((bidx & 63) == lane) ? (bidx >> 6) : -1;
#pragma unroll
      for (int m = 0; m < 16; ++m)
        if (m == kill) c0[m] = -3.0e38f;
      lbest = c0[0];
      lidx = 0;
#pragma unroll
      for (int m = 1; m < 16; ++m)
        if (c0[m] > lbest) { lbest = c0[m]; lidx = m; }
    }
    float mx = wv[0];
#pragma unroll
    for (int m = 1; m < KTOP; ++m) mx = fmaxf(mx, wv[m]);
    float ssum = 0.f;
#pragma unroll
    for (int m = 0; m < KTOP; ++m) {
      wv[m] = __expf(wv[m] - mx);
      ssum += wv[m];
    }
    float inv = 1.f / ssum;
    if (lane == 0) {
#pragma unroll
      for (int m = 0; m < KTOP; ++m) {
        wvs[m] = wv[m] * inv;
        wis[m] = wiR[m];
      }
    }
  } else {
    int ft = (wave < sel ? wave : wave - 1) * 64 + lane;  // 0..191
    if (ft < 16) Csp[ft] = 0.f;                   // front pad
    else if (ft < 32) Csp[1040 + ft - 16] = 0.f;  // back pad
  }
  __syncthreads();

  // ---- aggregate (clamped shift) + residual; t = tid + 256*i (stride-1 lanes) ----
  {
    float r[4];
#pragma unroll
    for (int i = 0; i < 4; ++i) r[i] = xT[base + tid + 256 * i];
#pragma unroll
    for (int k = 0; k < KTOP; ++k) {
      float w = wvs[k];
      int wi = wis[k];
#pragma unroll
      for (int i = 0; i < 4; ++i) {
        int p = wi + tid + 256 * i;
        p = p < (LL - 1) ? p : (LL - 1);
        r[i] += w * Vs[p];
      }
    }
#pragma unroll
    for (int i = 0; i < 4; ++i) Csp[16 + tid + 256 * i] = r[i];
  }
  __syncthreads();

  // ---- series_decomp #1 -> bf16 chan-major ----
  {
    int t0 = tid * 4;
    float buf[28];
#pragma unroll
    for (int qd = 0; qd < 7; ++qd)
      *(float4*)&buf[qd * 4] = *(const float4*)&Csp[t0 + 4 + qd * 4];
    float s = 0.f;
#pragma unroll
    for (int m = 0; m < 25; ++m) s += buf[m];
    ushort4 o;
    o.x = f2bf(buf[12] - s * (1.0f / 25.0f));
    s += buf[25] - buf[0];
    o.y = f2bf(buf[13] - s * (1.0f / 25.0f));
    s += buf[26] - buf[1];
    o.z = f2bf(buf[14] - s * (1.0f / 25.0f));
    s += buf[27] - buf[2];
    o.w = f2bf(buf[15] - s * (1.0f / 25.0f));
    *(ushort4*)&xsbT[base + t0] = o;
  }
}

// ======== xsbT [c][t] bf16 -> xsb [t][c] bf16 ========
__global__ __launch_bounds__(256) void k_castT(const unsigned short* __restrict__ src,
                                               unsigned short* __restrict__ dst) {
  __shared__ unsigned short T[64][68];
  int b = blockIdx.z;
  int t0 = blockIdx.x * 64, c0 = blockIdx.y * 64;
  int tid = threadIdx.x;
  int lane = tid & 63, r4 = tid >> 6;
#pragma unroll
  for (int it = 0; it < 16; ++it) {
    int cl = it * 4 + r4;
    T[lane][cl] = src[((size_t)b * 512 + c0 + cl) * LL + t0 + lane];
  }
  __syncthreads();
  int tl = tid >> 2, cq = (tid & 3) * 16;
  unsigned short* d = dst + ((size_t)b * LL + t0 + tl) * 512 + c0 + cq;
#pragma unroll
  for (int j = 0; j < 16; j += 4) {
    ushort4 u;
    u.x = T[tl][cq + j]; u.y = T[tl][cq + j + 1];
    u.z = T[tl][cq + j + 2]; u.w = T[tl][cq + j + 3];
    *(ushort4*)&d[j] = u;
  }
}

// ======== final decomp: s2T [c][t] f32 -> out [t][c] f32 ========
#define DCH 32
__global__ __launch_bounds__(256) void k_decomp2T(const float* __restrict__ s2T,
                                                  float* __restrict__ out) {
  __shared__ float T[DCH][289];
  int b = blockIdx.z, c0 = blockIdx.y * DCH, t0 = blockIdx.x * 256;
  int tid = threadIdx.x;
  {
    int row = tid >> 3, j0 = tid & 7;
    const float* src = s2T + ((size_t)b * 512 + c0 + row) * LL;
#pragma unroll
    for (int i = 0; i < 9; ++i) {
      int col = (j0 + i * 8) * 4;
      int t = t0 - 16 + col;
      float4 v = make_float4(0.f, 0.f, 0.f, 0.f);
      if (t >= 0 && t < LL) v = *(const float4*)&src[t];
      *(float4*)&T[row][col] = v;
    }
  }
  __syncthreads();
  int c = tid & 31, tg = tid >> 5;
  float sum = 0.f;
  int basec = tg * 32 + 4;
#pragma unroll
  for (int j = 0; j < 25; ++j) sum += T[c][basec + j];
  float* orow = out + ((size_t)b * LL + t0 + tg * 32) * 512 + c0 + c;
#pragma unroll 1
  for (int s = 0; s < 32; ++s) {
    float center = T[c][tg * 32 + 16 + s];
    orow[(size_t)s * 512] = center - sum * (1.f / 25.f);
    sum += T[c][basec + 25 + s] - T[c][basec + s];
  }
}

// ======== launch ========
extern "C" void kernel_launch(void* const* d_in, const int* in_sizes, int n_in,
                              void* d_out, int out_size, void* d_ws, size_t ws_size,
                              hipStream_t stream) {
  const float* x  = (const float*)d_in[0];
  const float* Wq = (const float*)d_in[1];
  const float* bq = (const float*)d_in[2];
  const float* Wk = (const float*)d_in[3];
  const float* bk = (const float*)d_in[4];
  const float* Wv = (const float*)d_in[5];
  const float* bv = (const float*)d_in[6];
  const float* W1 = (const float*)d_in[7];
  const float* b1 = (const float*)d_in[8];
  const float* W2 = (const float*)d_in[9];
  const float* b2 = (const float*)d_in[10];
  float* out = (float*)d_out;
  char* w = (char*)d_ws;

  // bytes: [0,4SZ) xT f32 (later h1 bf16 [0,2SZ) + xsb bf16 [2SZ,4SZ))
  //        [4SZ,6SZ) Q bf16 -> xsbT ; [6SZ,8SZ) K bf16
  //        [8SZ,12SZ) V f32 -> s2T ; [12SZ,..) packed weights ; [14SZ,16SZ) xb bf16
  float* xT             = (float*)w;
  unsigned short* Qbf   = (unsigned short*)(w + (size_t)SZ * 4);
  unsigned short* Kbf   = Qbf + SZ;
  float* Vf             = (float*)(w + (size_t)SZ * 8);
  unsigned short* WqkvT = (unsigned short*)(w + (size_t)SZ * 12);
  unsigned short* W1T   = WqkvT + 1536 * 512;
  unsigned short* W2T   = W1T + 512 * 512;
  float* bqkv           = (float*)(W2T + 512 * 512);
  unsigned short* xb    = (unsigned short*)(w + (size_t)SZ * 14);
  unsigned short* h1    = (unsigned short*)w;
  unsigned short* xsb   = (unsigned short*)(w + (size_t)SZ * 2);
  unsigned short* xsbT  = Qbf;
  float* s2T            = Vf;

  k_transpose<<<dim3(16, 8, NB), 256, 0, stream>>>(x, xT, xb);
  k_packall<<<dim3(8, 8, 5), 256, 0, stream>>>(Wq, Wk, Wv, W1, W2, bq, bk, bv,
                                               WqkvT, W1T, W2T, bqkv);

  k_mfma<0><<<dim3(768), 256, 0, stream>>>(xb, WqkvT, bqkv, nullptr, Qbf, Vf, 12);

  k_autocorr<<<dim3(NB * DD), 256, 0, stream>>>(Qbf, Kbf, Vf, xT, xsbT);

  k_castT<<<dim3(16, 8, NB), 256, 0, stream>>>(xsbT, xsb);

  k_mfma<1><<<dim3(256), 256, 0, stream>>>(xsb, W1T, b1, nullptr, h1, nullptr, 4);
  k_mfma<2><<<dim3(256), 256, 0, stream>>>(h1, W2T, b2, xsbT, nullptr, s2T, 4);

  k_decomp2T<<<dim3(4, 16, NB), 256, 0, stream>>>(s2T, out);
}